// Round 1
// baseline (446.562 us; speedup 1.0000x reference)
//
#include <hip/hip_runtime.h>
#include <hip/hip_bf16.h>

typedef __hip_bfloat16 bf16;
typedef __hip_bfloat162 bf162;

#define N_AUTHOR 20000
#define N_PAPER  40000
#define NEDGE    400000
#define HID      128
#define HEADS    8
#define DIMH     16
#define NCLS     16

typedef short short4v __attribute__((ext_vector_type(4)));
typedef short short8v __attribute__((ext_vector_type(8)));
typedef float f32x4   __attribute__((ext_vector_type(4)));

__device__ __forceinline__ bf162 mk2(float a, float b){
    bf162 r; r.x = __float2bfloat16(a); r.y = __float2bfloat16(b); return r;
}
__device__ __forceinline__ float b2f(short s){
    return __uint_as_float(((unsigned)(unsigned short)s) << 16);
}
__device__ __forceinline__ short f2bs(float v){
    unsigned u = __float_as_uint(v);
    unsigned r = (u + 0x7FFFu + ((u >> 16) & 1u)) >> 16;
    return (short)r;
}
__device__ __forceinline__ float fastrcp(float x){ return __builtin_amdgcn_rcpf(x); }

__device__ __forceinline__ float fast_tanh(float x){
    x = fminf(fmaxf(x, -15.f), 15.f);
    float e = __expf(2.f * x);
    return 1.f - 2.f * fastrcp(e + 1.f);
}

// ---------------------------------------------------------------------------
// LDS-free bf16 MFMA GEMM body; B-loads hoisted 16 at a time (2 kc rounds).
// A bf16 [M][KDIM]; Wt bf16 TRANSPOSED [128][KDIM].
// ---------------------------------------------------------------------------
template<int KDIM, int EPI>
__device__ __forceinline__ void bgemm_body(
    const bf16* __restrict__ A, const bf16* __restrict__ Wt, const float* __restrict__ Bb,
    bf16* __restrict__ C, const float* __restrict__ qv, float* __restrict__ score,
    int M, int brow, float* red)
{
    const int tid  = threadIdx.x;
    const int lane = tid & 63;
    const int wv   = tid >> 6;
    const int lr   = lane & 15;
    const int quad = lane >> 4;
    const int row0 = brow * 64 + wv * 16;
    const int arow_i = row0 + lr;
    const bool rowok = arow_i < M;
    const bf16* arow = A + (long)arow_i * KDIM;

    short8v afrag[KDIM / 32];
    #pragma unroll
    for (int kc = 0; kc < KDIM / 32; kc++) {
        short8v f = {0,0,0,0,0,0,0,0};
        if (rowok) f = *(const short8v*)(arow + kc * 32 + quad * 8);
        afrag[kc] = f;
    }

    f32x4 acc[8];
    #pragma unroll
    for (int ct = 0; ct < 8; ct++) acc[ct] = (f32x4){0.f, 0.f, 0.f, 0.f};

    #pragma unroll
    for (int k0 = 0; k0 < KDIM / 32; k0 += 2) {
        short8v bf[2][8];
        #pragma unroll
        for (int u = 0; u < 2; u++)
            #pragma unroll
            for (int ct = 0; ct < 8; ct++)
                bf[u][ct] = *(const short8v*)(Wt + (long)(ct * 16 + lr) * KDIM + (k0 + u) * 32 + quad * 8);
        #pragma unroll
        for (int u = 0; u < 2; u++)
            #pragma unroll
            for (int ct = 0; ct < 8; ct++)
                acc[ct] = __builtin_amdgcn_mfma_f32_16x16x32_bf16(afrag[k0 + u], bf[u][ct], acc[ct], 0, 0, 0);
    }

    if (EPI == 0) {
        #pragma unroll
        for (int ct = 0; ct < 8; ct++) {
            float bc = Bb ? Bb[ct * 16 + lr] : 0.f;
            #pragma unroll
            for (int r = 0; r < 4; r++) {
                int orow = row0 + quad * 4 + r;
                if (orow < M)
                    C[(long)orow * HID + ct * 16 + lr] = __float2bfloat16(acc[ct][r] + bc);
            }
        }
    } else {
        float part = 0.f;
        #pragma unroll
        for (int ct = 0; ct < 8; ct++) {
            float bc = Bb ? Bb[ct * 16 + lr] : 0.f;
            float qc = qv[ct * 16 + lr];
            #pragma unroll
            for (int r = 0; r < 4; r++) {
                int orow = row0 + quad * 4 + r;
                if (orow < M) part += qc * fast_tanh(acc[ct][r] + bc);
            }
        }
        red[tid] = part;
        __syncthreads();
        for (int s = 128; s > 0; s >>= 1) {
            if (tid < s) red[tid] += red[tid + s];
            __syncthreads();
        }
        if (tid == 0) atomicAdd(score, red[0]);
    }
}

template<int KDIM, int EPI>
__global__ __launch_bounds__(256) void bgemm_pair_kernel(
    const bf16* __restrict__ A0, const bf16* __restrict__ Wt0, const float* __restrict__ Bb0,
    bf16* __restrict__ C0, float* __restrict__ score0, int M0, int NB0,
    const bf16* __restrict__ A1, const bf16* __restrict__ Wt1, const float* __restrict__ Bb1,
    bf16* __restrict__ C1, float* __restrict__ score1, int M1,
    const float* __restrict__ qv)
{
    __shared__ float red[256];
    const int bx = blockIdx.x;
    if (bx < NB0)
        bgemm_body<KDIM, EPI>(A0, Wt0, Bb0, C0, qv, score0, M0, bx, red);
    else
        bgemm_body<KDIM, EPI>(A1, Wt1, Bb1, C1, qv, score1, M1, bx - NB0, red);
}

// ---------------------------------------------------------------------------
// sizes for conversions / CSR
// ---------------------------------------------------------------------------
#define R_WA  (128 * 64)
#define R_PW  (4 * 128 * 128)
#define R_KW  (2 * 128 * 128)
#define NXA (N_AUTHOR * 64)
#define NXP (N_PAPER * HID)
#define CONV_W_TOT (R_WA + R_PW + R_KW)
#define CONV_X_TOT ((NXA + NXP) / 4)
#define CONV_TOT   (CONV_W_TOT + CONV_X_TOT)

#define CNT_OFF1 N_PAPER
#define CNT_OFF2 (N_PAPER + N_AUTHOR)
#define NDEST    (2 * N_PAPER + N_AUTHOR)
// 8-way copy-privatized counters (copy = blockIdx&7 -> XCD-local under
// round-robin dispatch; correctness independent of the mapping).
// CW ints per counter slot (8B spacing: 8 counters/64B line, same-copy only).
#define NCOPY 8
#define CW    2
#define CIDX(c, d) (((c) * NDEST + (d)) * CW)
#define CNT_TOT (NCOPY * NDEST * CW)
#define E3 (3 * NEDGE)
#define HIST_T (E3 / 4)

// ---------------------------------------------------------------------------
// Fused: hist3 (atomic rank capture into per-copy counters) + conversions.
// rank[i] packs copy(3b)|rank(13b); max per-dest degree ~50 << 8192.
// ---------------------------------------------------------------------------
__global__ __launch_bounds__(256) void conv_hist_kernel(
    const int* __restrict__ d0, const int* __restrict__ d1, const int* __restrict__ d2,
    int* __restrict__ cnt, unsigned short* __restrict__ rank, int HB,
    const float* __restrict__ Wa, const float* __restrict__ proj_w,
    const float* __restrict__ klin_w,
    const float* __restrict__ xa_f, const float* __restrict__ xp_f,
    bf16* __restrict__ wt_wa, bf16* __restrict__ wt_proj, bf16* __restrict__ wt_klin,
    bf16* __restrict__ xa, bf16* __restrict__ xp)
{
    int bx = blockIdx.x;
    if (bx < HB) {
        int c = bx & (NCOPY - 1);
        int* mycnt = cnt + c * NDEST * CW;
        int t = bx * 256 + threadIdx.x;
        if (t >= HIST_T) return;
        #pragma unroll
        for (int u = 0; u < 4; u++) {
            int i = t + u * HIST_T;
            int r;
            if (i < NEDGE)            r = atomicAdd(&mycnt[d0[i] * CW], 1);
            else if (i < 2*NEDGE)     r = atomicAdd(&mycnt[(CNT_OFF1 + d1[i - NEDGE]) * CW], 1);
            else                      r = atomicAdd(&mycnt[(CNT_OFF2 + d2[i - 2*NEDGE]) * CW], 1);
            rank[i] = (unsigned short)((c << 13) | r);
        }
        return;
    }
    int t = (bx - HB) * 256 + threadIdx.x;
    if (t < CONV_W_TOT) {
        int i = t;
        if (i < R_WA) {
            int n = i >> 6, k = i & 63;
            wt_wa[i] = __float2bfloat16(Wa[k * 128 + n]);
        } else if (i < R_WA + R_PW) {
            int j = i - R_WA;
            int m = j >> 14, r = j & 16383;
            int n = r >> 7, k = r & 127;
            wt_proj[j] = __float2bfloat16(proj_w[m * 16384 + k * 128 + n]);
        } else {
            int j = i - R_WA - R_PW;
            int m = j >> 14, r = j & 16383;
            int n = r >> 7, k = r & 127;
            wt_klin[j] = __float2bfloat16(klin_w[m * 16384 + k * 128 + n]);
        }
    } else if (t < CONV_TOT) {
        int i = (t - CONV_W_TOT) * 4;
        if (i < NXA) {
            float4 v = *(const float4*)(xa_f + i);
            xa[i]   = __float2bfloat16(v.x); xa[i+1] = __float2bfloat16(v.y);
            xa[i+2] = __float2bfloat16(v.z); xa[i+3] = __float2bfloat16(v.w);
        } else {
            int j = i - NXA;
            float4 v = *(const float4*)(xp_f + j);
            xp[j]   = __float2bfloat16(v.x); xp[j+1] = __float2bfloat16(v.y);
            xp[j+2] = __float2bfloat16(v.z); xp[j+3] = __float2bfloat16(v.w);
        }
    }
}

__device__ __forceinline__ int job_nd(int j){ return j == 1 ? N_AUTHOR : N_PAPER; }
__device__ __forceinline__ int job_off(int j){ return j == 0 ? 0 : (j == 1 ? CNT_OFF1 : CNT_OFF2); }

__global__ __launch_bounds__(256) void scan_a3_kernel(const int* __restrict__ cnt,
                                                      int* __restrict__ bsum)
{
    int j = blockIdx.y;
    int nd = job_nd(j), off = job_off(j);
    __shared__ int s[256];
    int tid = threadIdx.x;
    int i = blockIdx.x * 256 + tid;
    int v = 0;
    if (i < nd) {
        #pragma unroll
        for (int c = 0; c < NCOPY; c++) v += cnt[CIDX(c, off + i)];
    }
    s[tid] = v;
    __syncthreads();
    for (int st = 128; st > 0; st >>= 1) {
        if (tid < st) s[tid] += s[tid + st];
        __syncthreads();
    }
    if (tid == 0) bsum[j * 256 + blockIdx.x] = s[0];
}

__global__ __launch_bounds__(256) void scan_b3_kernel(int* __restrict__ bsum,
    int* __restrict__ roff0, int* __restrict__ roff1, int* __restrict__ roff2)
{
    int j = blockIdx.x;
    int nd = job_nd(j);
    int nb = (nd + 255) / 256;
    int* roff = j == 0 ? roff0 : (j == 1 ? roff1 : roff2);
    __shared__ int s[256];
    int tid = threadIdx.x;
    int v = (tid < nb) ? bsum[j * 256 + tid] : 0;
    s[tid] = v;
    __syncthreads();
    for (int off = 1; off < 256; off <<= 1) {
        int t = (tid >= off) ? s[tid - off] : 0;
        __syncthreads();
        s[tid] += t;
        __syncthreads();
    }
    if (tid < nb) bsum[j * 256 + tid] = s[tid] - v;
    if (tid == 255) roff[nd] = s[255];
}

// per-dest exclusive prefix -> roff; also convert per-copy counts into
// per-copy global base positions (in place in cnt).
__global__ __launch_bounds__(256) void scan_c3_kernel(int* __restrict__ cnt,
    const int* __restrict__ bsum,
    int* __restrict__ roff0, int* __restrict__ roff1, int* __restrict__ roff2)
{
    int j = blockIdx.y;
    int nd = job_nd(j), off = job_off(j);
    int* roff = j == 0 ? roff0 : (j == 1 ? roff1 : roff2);
    __shared__ int s[256];
    int tid = threadIdx.x;
    int i = blockIdx.x * 256 + tid;
    int cc[NCOPY];
    int v = 0;
    if (i < nd) {
        #pragma unroll
        for (int c = 0; c < NCOPY; c++) { cc[c] = cnt[CIDX(c, off + i)]; v += cc[c]; }
    }
    s[tid] = v;
    __syncthreads();
    for (int o = 1; o < 256; o <<= 1) {
        int t = (tid >= o) ? s[tid - o] : 0;
        __syncthreads();
        s[tid] += t;
        __syncthreads();
    }
    if (i < nd) {
        int base = bsum[j * 256 + blockIdx.x] + s[tid] - v;
        roff[i] = base;
        #pragma unroll
        for (int c = 0; c < NCOPY; c++) { cnt[CIDX(c, off + i)] = base; base += cc[c]; }
    }
}

// ---------------------------------------------------------------------------
// Fused: author input projection (bgemm K=64) + CSR fill (no atomics).
// Fill decodes copy|rank and indexes the per-copy base position.
// ---------------------------------------------------------------------------
__global__ __launch_bounds__(256) void fill_gemm_kernel(
    const bf16* __restrict__ A, const bf16* __restrict__ Wt, bf16* __restrict__ C,
    int M, int GAb,
    const int* __restrict__ s0, const int* __restrict__ d0,
    const int* __restrict__ s1, const int* __restrict__ d1,
    const int* __restrict__ s2, const int* __restrict__ d2,
    const int* __restrict__ cnt,
    const unsigned short* __restrict__ rank,
    unsigned short* __restrict__ c0, unsigned short* __restrict__ c1, unsigned short* __restrict__ c2)
{
    __shared__ float red[256];
    int bx = blockIdx.x;
    if (bx < GAb) {
        bgemm_body<64, 0>(A, Wt, nullptr, C, nullptr, nullptr, M, bx, red);
        return;
    }
    int t = (bx - GAb) * 256 + threadIdx.x;
    if (t >= HIST_T) return;
    #pragma unroll
    for (int u = 0; u < 4; u++) {
        int i = t + u * HIST_T;
        int rw = rank[i];
        int c = rw >> 13, rk = rw & 0x1FFF;
        if (i < NEDGE) {
            int d = d0[i];
            c0[cnt[CIDX(c, d)] + rk] = (unsigned short)s0[i];
        } else if (i < 2*NEDGE) {
            int e = i - NEDGE, d = d1[e];
            c1[cnt[CIDX(c, CNT_OFF1 + d)] + rk] = (unsigned short)s1[e];
        } else {
            int e = i - 2*NEDGE, d = d2[e];
            c2[cnt[CIDX(c, CNT_OFF2 + d)] + rk] = (unsigned short)s2[e];
        }
    }
}

// multi-output node attention dots
__global__ void node_att_multi_kernel(const bf16* __restrict__ xh,
    const float* __restrict__ A0, const float* __restrict__ A1,
    const float* __restrict__ A2, const float* __restrict__ A3,
    float* __restrict__ O0, float* __restrict__ O1,
    float* __restrict__ O2, float* __restrict__ O3, int N)
{
    int i = blockIdx.x * blockDim.x + threadIdx.x;
    if (i >= N * HEADS) return;
    int n = i >> 3, h = i & 7;
    const bf16* row = xh + (long)n * HID + h * DIMH;
    float x[DIMH];
    #pragma unroll
    for (int d = 0; d < DIMH; d++) x[d] = __bfloat162float(row[d]);
    if (A0) { float s = 0.f;
        #pragma unroll
        for (int d = 0; d < DIMH; d++) s += x[d] * A0[h*DIMH + d];
        O0[i] = s; }
    if (A1) { float s = 0.f;
        #pragma unroll
        for (int d = 0; d < DIMH; d++) s += x[d] * A1[h*DIMH + d];
        O1[i] = s; }
    if (A2) { float s = 0.f;
        #pragma unroll
        for (int d = 0; d < DIMH; d++) s += x[d] * A2[h*DIMH + d];
        O2[i] = s; }
    if (A3) { float s = 0.f;
        #pragma unroll
        for (int d = 0; d < DIMH; d++) s += x[d] * A3[h*DIMH + d];
        O3[i] = s; }
}

// ---------------------------------------------------------------------------
// Fused paper gather: 16 lanes per dest, lane owns 8 features, 4-deep batch.
// ---------------------------------------------------------------------------
__global__ __launch_bounds__(256) void paper_gather2_kernel(
    const int* __restrict__ roff0, const unsigned short* __restrict__ csrc0,
    const float* __restrict__ as0, const float* __restrict__ ad0,
    const bf16* __restrict__ xha,
    const int* __restrict__ roff2, const unsigned short* __restrict__ csrc2,
    const float* __restrict__ as2, const float* __restrict__ ad2,
    const bf16* __restrict__ xhp,
    bf16* __restrict__ out0, bf16* __restrict__ out2)
{
    int lane = threadIdx.x & 63;
    int li   = lane & 15;
    int sub  = lane >> 4;
    int w = blockIdx.x * 16 + (threadIdx.x >> 6) * 4 + sub;
    if (w >= N_PAPER) return;
    int h = li >> 1;

    int b0 = roff0[w], n0 = roff0[w + 1] - b0;
    int b2 = roff2[w], n2 = roff2[w + 1] - b2;
    float ad0v = ad0[(long)w * 8 + h];
    float ad2v = ad2[(long)w * 8 + h];
    float den0 = 0.f, den2 = 0.f;
    float acc0[8], acc2[8];
    #pragma unroll
    for (int j = 0; j < 8; j++) { acc0[j] = 0.f; acc2[j] = 0.f; }

    int nmax = n0 > n2 ? n0 : n2;
    int c0m = n0 > 0 ? n0 - 1 : 0;
    int c2m = n2 > 0 ? n2 - 1 : 0;
    for (int i = 0; i < nmax; i += 4) {
        int sA[4], sB[4];
        #pragma unroll
        for (int u = 0; u < 4; u++) {
            sA[u] = csrc0[b0 + min(i + u, c0m)];
            sB[u] = csrc2[b2 + min(i + u, c2m)];
        }
        float aA[4], aB[4];
        short8v xA[4], xB[4];
        #pragma unroll
        for (int u = 0; u < 4; u++) {
            aA[u] = as0[(long)sA[u] * 8 + h];
            xA[u] = *(const short8v*)(xha + (long)sA[u] * HID + li * 8);
            aB[u] = as2[(long)sB[u] * 8 + h];
            xB[u] = *(const short8v*)(xhp + (long)sB[u] * HID + li * 8);
        }
        #pragma unroll
        for (int u = 0; u < 4; u++) {
            float a = aA[u] + ad0v;
            a = a >= 0.f ? a : 0.2f * a;
            float wt = __expf(fminf(a, 60.f));
            wt = (i + u < n0) ? wt : 0.f;
            den0 += wt;
            #pragma unroll
            for (int j = 0; j < 8; j++)
                acc0[j] = fmaf(b2f(xA[u][j]), wt, acc0[j]);
            a = aB[u] + ad2v;
            a = a >= 0.f ? a : 0.2f * a;
            wt = __expf(fminf(a, 60.f));
            wt = (i + u < n2) ? wt : 0.f;
            den2 += wt;
            #pragma unroll
            for (int j = 0; j < 8; j++)
                acc2[j] = fmaf(b2f(xB[u][j]), wt, acc2[j]);
        }
    }
    float inv0 = fastrcp(den0 + 1e-16f);
    float inv2 = fastrcp(den2 + 1e-16f);
    short8v o0, o2;
    #pragma unroll
    for (int j = 0; j < 8; j++) {
        o0[j] = f2bs(fmaxf(acc0[j] * inv0, 0.f));
        o2[j] = f2bs(fmaxf(acc2[j] * inv2, 0.f));
    }
    *(short8v*)(out0 + (long)w * HID + li * 8) = o0;
    *(short8v*)(out2 + (long)w * HID + li * 8) = o2;
}

// single gather (author dest, layer 0 only)
__global__ __launch_bounds__(256) void edge_gather_kernel(
    const int* __restrict__ roff, const unsigned short* __restrict__ csrc,
    const float* __restrict__ as_, const float* __restrict__ ad_,
    const bf16* __restrict__ xh, bf16* __restrict__ out, int Ndst)
{
    int lane = threadIdx.x & 63;
    int li   = lane & 15;
    int sub  = lane >> 4;
    int w = blockIdx.x * 16 + (threadIdx.x >> 6) * 4 + sub;
    if (w >= Ndst) return;
    int h = li >> 1;
    int beg = roff[w], n = roff[w + 1] - beg;
    float adv = ad_[(long)w * 8 + h];
    float den = 0.f;
    float acc[8];
    #pragma unroll
    for (int j = 0; j < 8; j++) acc[j] = 0.f;
    int cm = n > 0 ? n - 1 : 0;
    for (int i = 0; i < n; i += 4) {
        int s[4];
        #pragma unroll
        for (int u = 0; u < 4; u++) s[u] = csrc[beg + min(i + u, cm)];
        float av[4]; short8v xv[4];
        #pragma unroll
        for (int u = 0; u < 4; u++) {
            av[u] = as_[(long)s[u] * 8 + h];
            xv[u] = *(const short8v*)(xh + (long)s[u] * HID + li * 8);
        }
        #pragma unroll
        for (int u = 0; u < 4; u++) {
            float a = av[u] + adv;
            a = a >= 0.f ? a : 0.2f * a;
            float wt = __expf(fminf(a, 60.f));
            wt = (i + u < n) ? wt : 0.f;
            den += wt;
            #pragma unroll
            for (int j = 0; j < 8; j++)
                acc[j] = fmaf(b2f(xv[u][j]), wt, acc[j]);
        }
    }
    float inv = fastrcp(den + 1e-16f);
    short8v o;
    #pragma unroll
    for (int j = 0; j < 8; j++) o[j] = f2bs(fmaxf(acc[j] * inv, 0.f));
    *(short8v*)(out + (long)w * HID + li * 8) = o;
}

// semantic combine: bf16 in, bf16 out
__global__ void combine_kernel(const bf16* __restrict__ a0, const bf16* __restrict__ a1,
                               const float* __restrict__ score, bf16* __restrict__ out, int n2)
{
    int i = blockIdx.x * blockDim.x + threadIdx.x;
    if (i >= n2) return;
    float s0 = score[0] * (1.f / N_PAPER);
    float s1 = score[1] * (1.f / N_PAPER);
    float m = fmaxf(s0, s1);
    float e0 = __expf(s0 - m), e1 = __expf(s1 - m);
    float inv = fastrcp(e0 + e1);
    float w0 = e0 * inv, w1 = e1 * inv;
    bf162 v0 = ((const bf162*)a0)[i];
    bf162 v1 = ((const bf162*)a1)[i];
    ((bf162*)out)[i] = mk2(w0 * __bfloat162float(v0.x) + w1 * __bfloat162float(v1.x),
                           w0 * __bfloat162float(v0.y) + w1 * __bfloat162float(v1.y));
}

// final linear fused with last-layer semantic combine
__global__ __launch_bounds__(256) void final_lin_fused_kernel(
    const bf16* __restrict__ a0, const bf16* __restrict__ a1,
    const float* __restrict__ score,
    const float* __restrict__ W, const float* __restrict__ B, float* __restrict__ out)
{
    __shared__ float Ws[HID * NCLS];
    int tid = threadIdx.x;
    for (int i = tid; i < HID * NCLS; i += 256) Ws[i] = W[i];
    __syncthreads();
    float s0 = score[0] * (1.f / N_PAPER);
    float s1 = score[1] * (1.f / N_PAPER);
    float m = fmaxf(s0, s1);
    float e0 = __expf(s0 - m), e1 = __expf(s1 - m);
    float inv = 1.f / (e0 + e1);
    float w0 = e0 * inv, w1 = e1 * inv;
    int i = blockIdx.x * 256 + tid;
    if (i >= N_PAPER * NCLS) return;
    int n = i >> 4, c = i & 15;
    float acc = B[c];
    const bf16* x0 = a0 + (long)n * HID;
    const bf16* x1 = a1 + (long)n * HID;
    #pragma unroll 16
    for (int k = 0; k < HID; k++)
        acc = fmaf(fmaf(w0, __bfloat162float(x0[k]), w1 * __bfloat162float(x1[k])),
                   Ws[k * NCLS + c], acc);
    out[i] = acc;
}

extern "C" void kernel_launch(void* const* d_in, const int* in_sizes, int n_in,
                              void* d_out, int out_size, void* d_ws, size_t ws_size,
                              hipStream_t stream)
{
    const float* x_author = (const float*)d_in[0];
    const float* x_paper  = (const float*)d_in[1];
    const float* Wa       = (const float*)d_in[2];
    const float* proj_w   = (const float*)d_in[3];
    const float* proj_b   = (const float*)d_in[4];
    const float* att_src  = (const float*)d_in[5];
    const float* att_dst  = (const float*)d_in[6];
    const float* klin_w   = (const float*)d_in[7];
    const float* klin_b   = (const float*)d_in[8];
    const float* qv       = (const float*)d_in[9];
    const float* lin_w    = (const float*)d_in[10];
    const float* lin_b    = (const float*)d_in[11];
    const int*  ei_w      = (const int*)d_in[12];
    const int*  ei_wb     = (const int*)d_in[13];
    const int*  ei_c      = (const int*)d_in[14];
    float* out = (float*)d_out;
    (void)ws_size; (void)in_sizes; (void)n_in; (void)out_size;

    char* base = (char*)d_ws;
    size_t off = 0;
    auto alloc = [&](size_t bytes) {
        void* p = base + off;
        off = (off + bytes + 255) & ~(size_t)255;
        return p;
    };
    bf16*  xh_a  = (bf16*) alloc((size_t)N_AUTHOR * HID * 2);
    bf16*  xh_p  = (bf16*) alloc((size_t)N_PAPER  * HID * 2);
    bf16*  buf_a = (bf16*) alloc((size_t)N_AUTHOR * HID * 2);
    bf16*  buf_p = (bf16*) alloc((size_t)N_PAPER  * HID * 2);
    bf16*  agg_p1= (bf16*) alloc((size_t)N_PAPER  * HID * 2);
    bf16*  xa    = (bf16*) alloc((size_t)N_AUTHOR * 64  * 2);
    bf16*  xp    = (bf16*) alloc((size_t)N_PAPER  * HID * 2);
    bf16*  wt_wa   = (bf16*)alloc((size_t)R_WA * 2);
    bf16*  wt_proj = (bf16*)alloc((size_t)R_PW * 2);
    bf16*  wt_klin = (bf16*)alloc((size_t)R_KW * 2);
    float* a_e0s = (float*)alloc((size_t)N_AUTHOR * HEADS * 4);
    float* a_e0d = (float*)alloc((size_t)N_PAPER  * HEADS * 4);
    float* a_e1s = (float*)alloc((size_t)N_PAPER  * HEADS * 4);
    float* a_e1d = (float*)alloc((size_t)N_AUTHOR * HEADS * 4);
    float* a_e2s = (float*)alloc((size_t)N_PAPER  * HEADS * 4);
    float* a_e2d = (float*)alloc((size_t)N_PAPER  * HEADS * 4);
    float* score  = (float*)alloc(64);
    int* roff0 = (int*)alloc((size_t)(N_PAPER  + 1) * 4);
    int* roff1 = (int*)alloc((size_t)(N_AUTHOR + 1) * 4);
    int* roff2 = (int*)alloc((size_t)(N_PAPER  + 1) * 4);
    unsigned short* csrc0 = (unsigned short*)alloc((size_t)NEDGE * 2 + 64);
    unsigned short* csrc1 = (unsigned short*)alloc((size_t)NEDGE * 2 + 64);
    unsigned short* csrc2 = (unsigned short*)alloc((size_t)NEDGE * 2 + 64);
    int* cnt   = (int*)alloc((size_t)CNT_TOT * 4);   // 8 copies, 8B-spaced
    unsigned short* rank = (unsigned short*)alloc((size_t)E3 * 2);
    int* bsum  = (int*)alloc(3 * 256 * 4);

    const int GA = (N_AUTHOR + 63) / 64;   // 313
    const int GP = (N_PAPER  + 63) / 64;   // 625
    const int NBMAX = (N_PAPER + 255) / 256;   // 157
    const int HB = (HIST_T + 255) / 256;       // 1172
    const int CONVB = (CONV_TOT + 255) / 256;

    // ---- fused hist + conversions (independent work overlapped) ----
    hipMemsetAsync(cnt, 0, (size_t)CNT_TOT * 4, stream);
    conv_hist_kernel<<<HB + CONVB, 256, 0, stream>>>(
        ei_w + NEDGE, ei_wb + NEDGE, ei_c + NEDGE, cnt, rank, HB,
        Wa, proj_w, klin_w, x_author, x_paper,
        wt_wa, wt_proj, wt_klin, xa, xp);
    scan_a3_kernel<<<dim3(NBMAX, 3), 256, 0, stream>>>(cnt, bsum);
    scan_b3_kernel<<<3, 256, 0, stream>>>(bsum, roff0, roff1, roff2);
    scan_c3_kernel<<<dim3(NBMAX, 3), 256, 0, stream>>>(cnt, bsum, roff0, roff1, roff2);
    // ---- fused CSR fill + author input projection ----
    fill_gemm_kernel<<<GA + HB, 256, 0, stream>>>(
        xa, wt_wa, buf_a, N_AUTHOR, GA,
        ei_w, ei_w + NEDGE, ei_wb, ei_wb + NEDGE, ei_c, ei_c + NEDGE,
        cnt, rank, csrc0, csrc1, csrc2);

    for (int l = 0; l < 2; l++) {
        const bool last = (l == 1);
        const bf16* cur_a = buf_a;
        const bf16* cur_p = (l == 0) ? xp : buf_p;
        const bf16* pw_a = wt_proj + (size_t)(l*2 + 0) * HID * HID;
        const bf16* pw_p = wt_proj + (size_t)(l*2 + 1) * HID * HID;
        const float* pb_a = proj_b + (size_t)(l*2 + 0) * HID;
        const float* pb_p = proj_b + (size_t)(l*2 + 1) * HID;

        bgemm_pair_kernel<128, 0><<<GA + GP, 256, 0, stream>>>(
            cur_a, pw_a, pb_a, xh_a, nullptr, N_AUTHOR, GA,
            cur_p, pw_p, pb_p, xh_p, nullptr, N_PAPER, nullptr);

        hipMemsetAsync(score, 0, 64, stream);

        const float* as0 = att_src + (size_t)(l*3 + 0) * HID;
        const float* ad0 = att_dst + (size_t)(l*3 + 0) * HID;
        const float* as1 = att_src + (size_t)(l*3 + 1) * HID;
        const float* ad1 = att_dst + (size_t)(l*3 + 1) * HID;
        const float* as2 = att_src + (size_t)(l*3 + 2) * HID;
        const float* ad2 = att_dst + (size_t)(l*3 + 2) * HID;

        node_att_multi_kernel<<<(N_AUTHOR*HEADS + 255)/256, 256, 0, stream>>>(
            xh_a, as0, last ? nullptr : ad1, nullptr, nullptr,
            a_e0s, a_e1d, nullptr, nullptr, N_AUTHOR);
        node_att_multi_kernel<<<(N_PAPER*HEADS + 255)/256, 256, 0, stream>>>(
            xh_p, ad0, last ? nullptr : as1, as2, ad2,
            a_e0d, a_e1s, a_e2s, a_e2d, N_PAPER);

        paper_gather2_kernel<<<(N_PAPER + 15)/16, 256, 0, stream>>>(
            roff0, csrc0, a_e0s, a_e0d, xh_a,
            roff2, csrc2, a_e2s, a_e2d, xh_p,
            buf_p, agg_p1);
        if (!last)
            edge_gather_kernel<<<(N_AUTHOR + 15)/16, 256, 0, stream>>>(
                roff1, csrc1, a_e1s, a_e1d, xh_p, buf_a, N_AUTHOR);

        const bf16* kw = wt_klin + (size_t)l * HID * HID;
        const float* kb = klin_b + (size_t)l * HID;
        const float* qq = qv     + (size_t)l * HID;
        bgemm_pair_kernel<128, 1><<<2 * GP, 256, 0, stream>>>(
            buf_p, kw, kb, (bf16*)nullptr, score + 0, N_PAPER, GP,
            agg_p1, kw, kb, (bf16*)nullptr, score + 1, N_PAPER, qq);

        if (!last)
            combine_kernel<<<(N_PAPER*HID/2 + 255)/256, 256, 0, stream>>>(
                buf_p, agg_p1, score, buf_p, N_PAPER*HID/2);
    }

    final_lin_fused_kernel<<<(N_PAPER*NCLS + 255)/256, 256, 0, stream>>>(
        buf_p, agg_p1, score, lin_w, lin_b, out);
}

// Round 2
// 427.545 us; speedup vs baseline: 1.0445x; 1.0445x over previous
//
#include <hip/hip_runtime.h>
#include <hip/hip_bf16.h>

typedef __hip_bfloat16 bf16;
typedef __hip_bfloat162 bf162;

#define N_AUTHOR 20000
#define N_PAPER  40000
#define NEDGE    400000
#define HID      128
#define HEADS    8
#define DIMH     16
#define NCLS     16

typedef short short8v __attribute__((ext_vector_type(8)));
typedef float f32x4   __attribute__((ext_vector_type(4)));

__device__ __forceinline__ float b2f(short s){
    return __uint_as_float(((unsigned)(unsigned short)s) << 16);
}
__device__ __forceinline__ short f2bs(float v){
    unsigned u = __float_as_uint(v);
    unsigned r = (u + 0x7FFFu + ((u >> 16) & 1u)) >> 16;
    return (short)r;
}
__device__ __forceinline__ float fastrcp(float x){ return __builtin_amdgcn_rcpf(x); }

__device__ __forceinline__ float fast_tanh(float x){
    x = fminf(fmaxf(x, -15.f), 15.f);
    float e = __expf(2.f * x);
    return 1.f - 2.f * fastrcp(e + 1.f);
}

// ---------------------------------------------------------------------------
// LDS-free bf16 MFMA GEMM body. A bf16 [M][KDIM]; Wt bf16 TRANSPOSED [128][KDIM].
// BLEND: A-fragment = bf16(w0*A + w1*A2) on the fly (replaces combine_kernel).
// ---------------------------------------------------------------------------
template<int KDIM, int EPI, int BLEND>
__device__ __forceinline__ void bgemm_body(
    const bf16* __restrict__ A, const bf16* __restrict__ A2, float w0, float w1,
    const bf16* __restrict__ Wt, const float* __restrict__ Bb,
    bf16* __restrict__ C, const float* __restrict__ qv, float* __restrict__ score,
    int M, int brow, float* red)
{
    const int tid  = threadIdx.x;
    const int lane = tid & 63;
    const int wv   = tid >> 6;
    const int lr   = lane & 15;
    const int quad = lane >> 4;
    const int row0 = brow * 64 + wv * 16;
    const int arow_i = row0 + lr;
    const bool rowok = arow_i < M;
    const bf16* arow  = A  + (long)arow_i * KDIM;
    const bf16* arow2 = BLEND ? (A2 + (long)arow_i * KDIM) : nullptr;

    short8v afrag[KDIM / 32];
    #pragma unroll
    for (int kc = 0; kc < KDIM / 32; kc++) {
        short8v f = {0,0,0,0,0,0,0,0};
        if (rowok) {
            f = *(const short8v*)(arow + kc * 32 + quad * 8);
            if (BLEND) {
                short8v g = *(const short8v*)(arow2 + kc * 32 + quad * 8);
                #pragma unroll
                for (int j = 0; j < 8; j++)
                    f[j] = f2bs(w0 * b2f(f[j]) + w1 * b2f(g[j]));
            }
        }
        afrag[kc] = f;
    }

    f32x4 acc[8];
    #pragma unroll
    for (int ct = 0; ct < 8; ct++) acc[ct] = (f32x4){0.f, 0.f, 0.f, 0.f};

    #pragma unroll
    for (int k0 = 0; k0 < KDIM / 32; k0 += 2) {
        short8v bf[2][8];
        #pragma unroll
        for (int u = 0; u < 2; u++)
            #pragma unroll
            for (int ct = 0; ct < 8; ct++)
                bf[u][ct] = *(const short8v*)(Wt + (long)(ct * 16 + lr) * KDIM + (k0 + u) * 32 + quad * 8);
        #pragma unroll
        for (int u = 0; u < 2; u++)
            #pragma unroll
            for (int ct = 0; ct < 8; ct++)
                acc[ct] = __builtin_amdgcn_mfma_f32_16x16x32_bf16(afrag[k0 + u], bf[u][ct], acc[ct], 0, 0, 0);
    }

    if (EPI == 0) {
        #pragma unroll
        for (int ct = 0; ct < 8; ct++) {
            float bc = Bb ? Bb[ct * 16 + lr] : 0.f;
            #pragma unroll
            for (int r = 0; r < 4; r++) {
                int orow = row0 + quad * 4 + r;
                if (orow < M)
                    C[(long)orow * HID + ct * 16 + lr] = __float2bfloat16(acc[ct][r] + bc);
            }
        }
    } else {
        float part = 0.f;
        #pragma unroll
        for (int ct = 0; ct < 8; ct++) {
            float bc = Bb ? Bb[ct * 16 + lr] : 0.f;
            float qc = qv[ct * 16 + lr];
            #pragma unroll
            for (int r = 0; r < 4; r++) {
                int orow = row0 + quad * 4 + r;
                if (orow < M) part += qc * fast_tanh(acc[ct][r] + bc);
            }
        }
        red[tid] = part;
        __syncthreads();
        for (int s = 128; s > 0; s >>= 1) {
            if (tid < s) red[tid] += red[tid + s];
            __syncthreads();
        }
        if (tid == 0) atomicAdd(score, red[0]);
    }
}

// pair kernel: side0 plain; side1 optionally blended (B1)
template<int KDIM, int EPI, int B1>
__global__ __launch_bounds__(256) void bgemm_pair_kernel(
    const bf16* __restrict__ A0, const bf16* __restrict__ Wt0, const float* __restrict__ Bb0,
    bf16* __restrict__ C0, float* __restrict__ score0, int M0, int NB0,
    const bf16* __restrict__ A1, const bf16* __restrict__ A1b, const float* __restrict__ scw,
    const bf16* __restrict__ Wt1, const float* __restrict__ Bb1,
    bf16* __restrict__ C1, float* __restrict__ score1, int M1,
    const float* __restrict__ qv)
{
    __shared__ float red[256];
    const int bx = blockIdx.x;
    if (bx < NB0) {
        bgemm_body<KDIM, EPI, 0>(A0, nullptr, 0.f, 0.f, Wt0, Bb0, C0, qv, score0, M0, bx, red);
    } else {
        float w0 = 0.f, w1 = 0.f;
        if (B1) {
            float s0 = scw[0] * (1.f / N_PAPER);
            float s1 = scw[1] * (1.f / N_PAPER);
            float m = fmaxf(s0, s1);
            float e0 = __expf(s0 - m), e1 = __expf(s1 - m);
            float inv = fastrcp(e0 + e1);
            w0 = e0 * inv; w1 = e1 * inv;
        }
        bgemm_body<KDIM, EPI, B1>(A1, A1b, w0, w1, Wt1, Bb1, C1, qv, score1, M1, bx - NB0, red);
    }
}

// ---------------------------------------------------------------------------
// sizes for conversions / CSR
// ---------------------------------------------------------------------------
#define R_WA  (128 * 64)
#define R_PW  (4 * 128 * 128)
#define R_KW  (2 * 128 * 128)
#define NXA (N_AUTHOR * 64)
#define NXP (N_PAPER * HID)
#define CONV_W_TOT (R_WA + R_PW + R_KW)
#define CONV_X_TOT ((NXA + NXP) / 4)
#define CONV_TOT   (CONV_W_TOT + CONV_X_TOT)

#define CNT_OFF1 N_PAPER
#define CNT_OFF2 (N_PAPER + N_AUTHOR)
#define NDEST    (2 * N_PAPER + N_AUTHOR)
#define NCOPY 8
#define CW    2
#define CIDX(c, d) (((c) * NDEST + (d)) * CW)
#define CNT_TOT (NCOPY * NDEST * CW)
#define E3 (3 * NEDGE)
#define HIST_T (E3 / 4)

// pure conversions (fp32->bf16 weights transposed, activations)
__global__ __launch_bounds__(256) void conv_kernel(
    const float* __restrict__ Wa, const float* __restrict__ proj_w,
    const float* __restrict__ klin_w,
    const float* __restrict__ xa_f, const float* __restrict__ xp_f,
    bf16* __restrict__ wt_wa, bf16* __restrict__ wt_proj, bf16* __restrict__ wt_klin,
    bf16* __restrict__ xa, bf16* __restrict__ xp)
{
    int t = blockIdx.x * 256 + threadIdx.x;
    if (t < CONV_W_TOT) {
        int i = t;
        if (i < R_WA) {
            int n = i >> 6, k = i & 63;
            wt_wa[i] = __float2bfloat16(Wa[k * 128 + n]);
        } else if (i < R_WA + R_PW) {
            int j = i - R_WA;
            int m = j >> 14, r = j & 16383;
            int n = r >> 7, k = r & 127;
            wt_proj[j] = __float2bfloat16(proj_w[m * 16384 + k * 128 + n]);
        } else {
            int j = i - R_WA - R_PW;
            int m = j >> 14, r = j & 16383;
            int n = r >> 7, k = r & 127;
            wt_klin[j] = __float2bfloat16(klin_w[m * 16384 + k * 128 + n]);
        }
    } else if (t < CONV_TOT) {
        int i = (t - CONV_W_TOT) * 4;
        if (i < NXA) {
            float4 v = *(const float4*)(xa_f + i);
            xa[i]   = __float2bfloat16(v.x); xa[i+1] = __float2bfloat16(v.y);
            xa[i+2] = __float2bfloat16(v.z); xa[i+3] = __float2bfloat16(v.w);
        } else {
            int j = i - NXA;
            float4 v = *(const float4*)(xp_f + j);
            xp[j]   = __float2bfloat16(v.x); xp[j+1] = __float2bfloat16(v.y);
            xp[j+2] = __float2bfloat16(v.z); xp[j+3] = __float2bfloat16(v.w);
        }
    }
}

// ---------------------------------------------------------------------------
// Fused: hist (atomic-rate-bound, ~50us floor) + bufa K=64 GEMM + layer-0
// paper projection GEMM. GEMM blocks hide under the atomic window.
// ---------------------------------------------------------------------------
__global__ __launch_bounds__(256) void hist_gemm_kernel(
    const int* __restrict__ d0, const int* __restrict__ d1, const int* __restrict__ d2,
    int* __restrict__ cnt, unsigned short* __restrict__ rank, int HB,
    const bf16* __restrict__ xa, const bf16* __restrict__ wt_wa, bf16* __restrict__ buf_a, int GA64,
    const bf16* __restrict__ xp, const bf16* __restrict__ pw_p, const float* __restrict__ pb_p,
    bf16* __restrict__ xh_p)
{
    __shared__ float red[256];
    int bx = blockIdx.x;
    if (bx < HB) {
        int c = bx & (NCOPY - 1);
        int* mycnt = cnt + c * NDEST * CW;
        int t = bx * 256 + threadIdx.x;
        if (t >= HIST_T) return;
        #pragma unroll
        for (int u = 0; u < 4; u++) {
            int i = t + u * HIST_T;
            int r;
            if (i < NEDGE)            r = atomicAdd(&mycnt[d0[i] * CW], 1);
            else if (i < 2*NEDGE)     r = atomicAdd(&mycnt[(CNT_OFF1 + d1[i - NEDGE]) * CW], 1);
            else                      r = atomicAdd(&mycnt[(CNT_OFF2 + d2[i - 2*NEDGE]) * CW], 1);
            rank[i] = (unsigned short)((c << 13) | r);
        }
        return;
    }
    bx -= HB;
    if (bx < GA64) {
        bgemm_body<64, 0, 0>(xa, nullptr, 0.f, 0.f, wt_wa, nullptr, buf_a,
                             nullptr, nullptr, N_AUTHOR, bx, red);
        return;
    }
    bx -= GA64;
    bgemm_body<128, 0, 0>(xp, nullptr, 0.f, 0.f, pw_p, pb_p, xh_p,
                          nullptr, nullptr, N_PAPER, bx, red);
}

__device__ __forceinline__ int job_nd(int j){ return j == 1 ? N_AUTHOR : N_PAPER; }
__device__ __forceinline__ int job_off(int j){ return j == 0 ? 0 : (j == 1 ? CNT_OFF1 : CNT_OFF2); }

__global__ __launch_bounds__(256) void scan_a3_kernel(const int* __restrict__ cnt,
                                                      int* __restrict__ bsum)
{
    int j = blockIdx.y;
    int nd = job_nd(j), off = job_off(j);
    __shared__ int s[256];
    int tid = threadIdx.x;
    int i = blockIdx.x * 256 + tid;
    int v = 0;
    if (i < nd) {
        #pragma unroll
        for (int c = 0; c < NCOPY; c++) v += cnt[CIDX(c, off + i)];
    }
    s[tid] = v;
    __syncthreads();
    for (int st = 128; st > 0; st >>= 1) {
        if (tid < st) s[tid] += s[tid + st];
        __syncthreads();
    }
    if (tid == 0) bsum[j * 256 + blockIdx.x] = s[0];
}

// merged scan_b+scan_c: block base computed locally from bsum; per-dest
// exclusive prefix -> roff; per-copy counts -> global base positions in cnt.
__global__ __launch_bounds__(256) void scan_bc_kernel(int* __restrict__ cnt,
    const int* __restrict__ bsum,
    int* __restrict__ roff0, int* __restrict__ roff1, int* __restrict__ roff2)
{
    int j = blockIdx.y;
    int nd = job_nd(j), off = job_off(j);
    int* roff = j == 0 ? roff0 : (j == 1 ? roff1 : roff2);
    __shared__ int sb[256];
    __shared__ int s[256];
    int tid = threadIdx.x;
    int bx = blockIdx.x;
    int nb = (nd + 255) / 256;
    int bvt = (tid < nb) ? bsum[j * 256 + tid] : 0;
    sb[tid] = bvt;
    __syncthreads();
    for (int o = 1; o < 256; o <<= 1) {
        int t = (tid >= o) ? sb[tid - o] : 0;
        __syncthreads();
        sb[tid] += t;
        __syncthreads();
    }
    int base0 = sb[bx] - bsum[j * 256 + bx];   // exclusive block base
    int i = bx * 256 + tid;
    int cc[NCOPY];
    int v = 0;
    if (i < nd) {
        #pragma unroll
        for (int c = 0; c < NCOPY; c++) { cc[c] = cnt[CIDX(c, off + i)]; v += cc[c]; }
    }
    s[tid] = v;
    __syncthreads();
    for (int o = 1; o < 256; o <<= 1) {
        int t = (tid >= o) ? s[tid - o] : 0;
        __syncthreads();
        s[tid] += t;
        __syncthreads();
    }
    if (i < nd) {
        int base = base0 + s[tid] - v;
        roff[i] = base;
        #pragma unroll
        for (int c = 0; c < NCOPY; c++) { cnt[CIDX(c, off + i)] = base; base += cc[c]; }
    }
    if (bx == 0 && tid == 0) roff[nd] = NEDGE;   // each edge type has exactly NEDGE edges
}

// ---------------------------------------------------------------------------
// Fused: CSR fill + layer-0 author projection + layer-0 paper node-att dots.
// ---------------------------------------------------------------------------
__global__ __launch_bounds__(256) void fill_natt_kernel(
    const int* __restrict__ s0, const int* __restrict__ d0,
    const int* __restrict__ s1, const int* __restrict__ d1,
    const int* __restrict__ s2, const int* __restrict__ d2,
    const int* __restrict__ cnt, const unsigned short* __restrict__ rank,
    unsigned short* __restrict__ c0, unsigned short* __restrict__ c1, unsigned short* __restrict__ c2,
    int HB,
    const bf16* __restrict__ A, const bf16* __restrict__ Wt, const float* __restrict__ Bb,
    bf16* __restrict__ C, int GAb,
    const bf16* __restrict__ xh_p,
    const float* __restrict__ ad0v, const float* __restrict__ as1v,
    const float* __restrict__ as2v, const float* __restrict__ ad2v,
    float* __restrict__ o_e0d, float* __restrict__ o_e1s,
    float* __restrict__ o_e2s, float* __restrict__ o_e2d)
{
    __shared__ float red[256];
    int bx = blockIdx.x;
    if (bx < HB) {
        int t = bx * 256 + threadIdx.x;
        if (t >= HIST_T) return;
        #pragma unroll
        for (int u = 0; u < 4; u++) {
            int i = t + u * HIST_T;
            int rw = rank[i];
            int c = rw >> 13, rk = rw & 0x1FFF;
            if (i < NEDGE) {
                int d = d0[i];
                c0[cnt[CIDX(c, d)] + rk] = (unsigned short)s0[i];
            } else if (i < 2*NEDGE) {
                int e = i - NEDGE, d = d1[e];
                c1[cnt[CIDX(c, CNT_OFF1 + d)] + rk] = (unsigned short)s1[e];
            } else {
                int e = i - 2*NEDGE, d = d2[e];
                c2[cnt[CIDX(c, CNT_OFF2 + d)] + rk] = (unsigned short)s2[e];
            }
        }
        return;
    }
    bx -= HB;
    if (bx < GAb) {
        bgemm_body<128, 0, 0>(A, nullptr, 0.f, 0.f, Wt, Bb, C,
                              nullptr, nullptr, N_AUTHOR, bx, red);
        return;
    }
    bx -= GAb;
    int i = bx * 256 + threadIdx.x;
    if (i >= N_PAPER * HEADS) return;
    int n = i >> 3, h = i & 7;
    const bf16* row = xh_p + (long)n * HID + h * DIMH;
    float x[DIMH];
    #pragma unroll
    for (int d = 0; d < DIMH; d++) x[d] = __bfloat162float(row[d]);
    float sA = 0.f, sB = 0.f, sC = 0.f, sD = 0.f;
    #pragma unroll
    for (int d = 0; d < DIMH; d++) {
        sA += x[d] * ad0v[h*DIMH + d];
        sB += x[d] * as1v[h*DIMH + d];
        sC += x[d] * as2v[h*DIMH + d];
        sD += x[d] * ad2v[h*DIMH + d];
    }
    o_e0d[i] = sA; o_e1s[i] = sB; o_e2s[i] = sC; o_e2d[i] = sD;
}

// multi-output node attention dots (layer-0 author side)
__global__ void node_att_multi_kernel(const bf16* __restrict__ xh,
    const float* __restrict__ A0, const float* __restrict__ A1,
    float* __restrict__ O0, float* __restrict__ O1, int N)
{
    int i = blockIdx.x * blockDim.x + threadIdx.x;
    if (i >= N * HEADS) return;
    int n = i >> 3, h = i & 7;
    const bf16* row = xh + (long)n * HID + h * DIMH;
    float x[DIMH];
    #pragma unroll
    for (int d = 0; d < DIMH; d++) x[d] = __bfloat162float(row[d]);
    if (A0) { float s = 0.f;
        #pragma unroll
        for (int d = 0; d < DIMH; d++) s += x[d] * A0[h*DIMH + d];
        O0[i] = s; }
    if (A1) { float s = 0.f;
        #pragma unroll
        for (int d = 0; d < DIMH; d++) s += x[d] * A1[h*DIMH + d];
        O1[i] = s; }
}

// layer-1 fused node-att (author as0 only; paper ad0/as2/ad2)
__global__ __launch_bounds__(256) void natt_l1_kernel(
    const bf16* __restrict__ xh_a, const float* __restrict__ as0, float* __restrict__ a_e0s, int AB,
    const bf16* __restrict__ xh_p, const float* __restrict__ ad0,
    const float* __restrict__ as2, const float* __restrict__ ad2,
    float* __restrict__ a_e0d, float* __restrict__ a_e2s, float* __restrict__ a_e2d)
{
    int bx = blockIdx.x, tid = threadIdx.x;
    if (bx < AB) {
        int i = bx * 256 + tid;
        if (i >= N_AUTHOR * HEADS) return;
        int n = i >> 3, h = i & 7;
        const bf16* row = xh_a + (long)n * HID + h * DIMH;
        float s = 0.f;
        #pragma unroll
        for (int d = 0; d < DIMH; d++) s += __bfloat162float(row[d]) * as0[h*DIMH + d];
        a_e0s[i] = s;
        return;
    }
    int i = (bx - AB) * 256 + tid;
    if (i >= N_PAPER * HEADS) return;
    int n = i >> 3, h = i & 7;
    const bf16* row = xh_p + (long)n * HID + h * DIMH;
    float x[DIMH];
    #pragma unroll
    for (int d = 0; d < DIMH; d++) x[d] = __bfloat162float(row[d]);
    float sA = 0.f, sC = 0.f, sD = 0.f;
    #pragma unroll
    for (int d = 0; d < DIMH; d++) {
        sA += x[d] * ad0[h*DIMH + d];
        sC += x[d] * as2[h*DIMH + d];
        sD += x[d] * ad2[h*DIMH + d];
    }
    a_e0d[i] = sA; a_e2s[i] = sC; a_e2d[i] = sD;
}

// ---------------------------------------------------------------------------
// gather bodies (16 lanes per dest, lane owns 8 features, 4-deep batch)
// ---------------------------------------------------------------------------
__device__ __forceinline__ void paper_gather2_dev(int bid,
    const int* __restrict__ roff0, const unsigned short* __restrict__ csrc0,
    const float* __restrict__ as0, const float* __restrict__ ad0,
    const bf16* __restrict__ xha,
    const int* __restrict__ roff2, const unsigned short* __restrict__ csrc2,
    const float* __restrict__ as2, const float* __restrict__ ad2,
    const bf16* __restrict__ xhp,
    bf16* __restrict__ out0, bf16* __restrict__ out2)
{
    int lane = threadIdx.x & 63;
    int li   = lane & 15;
    int sub  = lane >> 4;
    int w = bid * 16 + (threadIdx.x >> 6) * 4 + sub;
    if (w >= N_PAPER) return;
    int h = li >> 1;

    int b0 = roff0[w], n0 = roff0[w + 1] - b0;
    int b2 = roff2[w], n2 = roff2[w + 1] - b2;
    float ad0v = ad0[(long)w * 8 + h];
    float ad2v = ad2[(long)w * 8 + h];
    float den0 = 0.f, den2 = 0.f;
    float acc0[8], acc2[8];
    #pragma unroll
    for (int j = 0; j < 8; j++) { acc0[j] = 0.f; acc2[j] = 0.f; }

    int nmax = n0 > n2 ? n0 : n2;
    int c0m = n0 > 0 ? n0 - 1 : 0;
    int c2m = n2 > 0 ? n2 - 1 : 0;
    for (int i = 0; i < nmax; i += 4) {
        int sA[4], sB[4];
        #pragma unroll
        for (int u = 0; u < 4; u++) {
            sA[u] = csrc0[b0 + min(i + u, c0m)];
            sB[u] = csrc2[b2 + min(i + u, c2m)];
        }
        float aA[4], aB[4];
        short8v xA[4], xB[4];
        #pragma unroll
        for (int u = 0; u < 4; u++) {
            aA[u] = as0[(long)sA[u] * 8 + h];
            xA[u] = *(const short8v*)(xha + (long)sA[u] * HID + li * 8);
            aB[u] = as2[(long)sB[u] * 8 + h];
            xB[u] = *(const short8v*)(xhp + (long)sB[u] * HID + li * 8);
        }
        #pragma unroll
        for (int u = 0; u < 4; u++) {
            float a = aA[u] + ad0v;
            a = a >= 0.f ? a : 0.2f * a;
            float wt = __expf(fminf(a, 60.f));
            wt = (i + u < n0) ? wt : 0.f;
            den0 += wt;
            #pragma unroll
            for (int j = 0; j < 8; j++)
                acc0[j] = fmaf(b2f(xA[u][j]), wt, acc0[j]);
            a = aB[u] + ad2v;
            a = a >= 0.f ? a : 0.2f * a;
            wt = __expf(fminf(a, 60.f));
            wt = (i + u < n2) ? wt : 0.f;
            den2 += wt;
            #pragma unroll
            for (int j = 0; j < 8; j++)
                acc2[j] = fmaf(b2f(xB[u][j]), wt, acc2[j]);
        }
    }
    float inv0 = fastrcp(den0 + 1e-16f);
    float inv2 = fastrcp(den2 + 1e-16f);
    short8v o0, o2;
    #pragma unroll
    for (int j = 0; j < 8; j++) {
        o0[j] = f2bs(fmaxf(acc0[j] * inv0, 0.f));
        o2[j] = f2bs(fmaxf(acc2[j] * inv2, 0.f));
    }
    *(short8v*)(out0 + (long)w * HID + li * 8) = o0;
    *(short8v*)(out2 + (long)w * HID + li * 8) = o2;
}

__device__ __forceinline__ void edge_gather_dev(int bid,
    const int* __restrict__ roff, const unsigned short* __restrict__ csrc,
    const float* __restrict__ as_, const float* __restrict__ ad_,
    const bf16* __restrict__ xh, bf16* __restrict__ out, int Ndst)
{
    int lane = threadIdx.x & 63;
    int li   = lane & 15;
    int sub  = lane >> 4;
    int w = bid * 16 + (threadIdx.x >> 6) * 4 + sub;
    if (w >= Ndst) return;
    int h = li >> 1;
    int beg = roff[w], n = roff[w + 1] - beg;
    float adv = ad_[(long)w * 8 + h];
    float den = 0.f;
    float acc[8];
    #pragma unroll
    for (int j = 0; j < 8; j++) acc[j] = 0.f;
    int cm = n > 0 ? n - 1 : 0;
    for (int i = 0; i < n; i += 4) {
        int s[4];
        #pragma unroll
        for (int u = 0; u < 4; u++) s[u] = csrc[beg + min(i + u, cm)];
        float av[4]; short8v xv[4];
        #pragma unroll
        for (int u = 0; u < 4; u++) {
            av[u] = as_[(long)s[u] * 8 + h];
            xv[u] = *(const short8v*)(xh + (long)s[u] * HID + li * 8);
        }
        #pragma unroll
        for (int u = 0; u < 4; u++) {
            float a = av[u] + adv;
            a = a >= 0.f ? a : 0.2f * a;
            float wt = __expf(fminf(a, 60.f));
            wt = (i + u < n) ? wt : 0.f;
            den += wt;
            #pragma unroll
            for (int j = 0; j < 8; j++)
                acc[j] = fmaf(b2f(xv[u][j]), wt, acc[j]);
        }
    }
    float inv = fastrcp(den + 1e-16f);
    short8v o;
    #pragma unroll
    for (int j = 0; j < 8; j++) o[j] = f2bs(fmaxf(acc[j] * inv, 0.f));
    *(short8v*)(out + (long)w * HID + li * 8) = o;
}

__global__ __launch_bounds__(256) void gather_fused_kernel(
    const int* __restrict__ roff0, const unsigned short* __restrict__ csrc0,
    const float* __restrict__ as0, const float* __restrict__ ad0,
    const bf16* __restrict__ xha,
    const int* __restrict__ roff2, const unsigned short* __restrict__ csrc2,
    const float* __restrict__ as2, const float* __restrict__ ad2,
    const bf16* __restrict__ xhp,
    bf16* __restrict__ out0, bf16* __restrict__ out2, int PB,
    const int* __restrict__ roff1, const unsigned short* __restrict__ csrc1,
    const float* __restrict__ as1, const float* __restrict__ ad1,
    bf16* __restrict__ out_a)
{
    int bx = blockIdx.x;
    if (bx < PB)
        paper_gather2_dev(bx, roff0, csrc0, as0, ad0, xha,
                          roff2, csrc2, as2, ad2, xhp, out0, out2);
    else
        edge_gather_dev(bx - PB, roff1, csrc1, as1, ad1, xhp, out_a, N_AUTHOR);
}

// final linear fused with last-layer semantic combine
__global__ __launch_bounds__(256) void final_lin_fused_kernel(
    const bf16* __restrict__ a0, const bf16* __restrict__ a1,
    const float* __restrict__ score,
    const float* __restrict__ W, const float* __restrict__ B, float* __restrict__ out)
{
    __shared__ float Ws[HID * NCLS];
    int tid = threadIdx.x;
    for (int i = tid; i < HID * NCLS; i += 256) Ws[i] = W[i];
    __syncthreads();
    float s0 = score[0] * (1.f / N_PAPER);
    float s1 = score[1] * (1.f / N_PAPER);
    float m = fmaxf(s0, s1);
    float e0 = __expf(s0 - m), e1 = __expf(s1 - m);
    float inv = 1.f / (e0 + e1);
    float w0 = e0 * inv, w1 = e1 * inv;
    int i = blockIdx.x * 256 + tid;
    if (i >= N_PAPER * NCLS) return;
    int n = i >> 4, c = i & 15;
    float acc = B[c];
    const bf16* x0 = a0 + (long)n * HID;
    const bf16* x1 = a1 + (long)n * HID;
    #pragma unroll 16
    for (int k = 0; k < HID; k++)
        acc = fmaf(fmaf(w0, __bfloat162float(x0[k]), w1 * __bfloat162float(x1[k])),
                   Ws[k * NCLS + c], acc);
    out[i] = acc;
}

extern "C" void kernel_launch(void* const* d_in, const int* in_sizes, int n_in,
                              void* d_out, int out_size, void* d_ws, size_t ws_size,
                              hipStream_t stream)
{
    const float* x_author = (const float*)d_in[0];
    const float* x_paper  = (const float*)d_in[1];
    const float* Wa       = (const float*)d_in[2];
    const float* proj_w   = (const float*)d_in[3];
    const float* proj_b   = (const float*)d_in[4];
    const float* att_src  = (const float*)d_in[5];
    const float* att_dst  = (const float*)d_in[6];
    const float* klin_w   = (const float*)d_in[7];
    const float* klin_b   = (const float*)d_in[8];
    const float* qv       = (const float*)d_in[9];
    const float* lin_w    = (const float*)d_in[10];
    const float* lin_b    = (const float*)d_in[11];
    const int*  ei_w      = (const int*)d_in[12];
    const int*  ei_wb     = (const int*)d_in[13];
    const int*  ei_c      = (const int*)d_in[14];
    float* out = (float*)d_out;
    (void)ws_size; (void)in_sizes; (void)n_in; (void)out_size;

    char* base = (char*)d_ws;
    size_t off = 0;
    auto alloc = [&](size_t bytes) {
        void* p = base + off;
        off = (off + bytes + 255) & ~(size_t)255;
        return p;
    };
    bf16*  xh_a  = (bf16*) alloc((size_t)N_AUTHOR * HID * 2);
    bf16*  xh_p  = (bf16*) alloc((size_t)N_PAPER  * HID * 2);
    bf16*  buf_a = (bf16*) alloc((size_t)N_AUTHOR * HID * 2);
    bf16*  buf_p = (bf16*) alloc((size_t)N_PAPER  * HID * 2);
    bf16*  agg_p1= (bf16*) alloc((size_t)N_PAPER  * HID * 2);
    bf16*  xa    = (bf16*) alloc((size_t)N_AUTHOR * 64  * 2);
    bf16*  xp    = (bf16*) alloc((size_t)N_PAPER  * HID * 2);
    bf16*  wt_wa   = (bf16*)alloc((size_t)R_WA * 2);
    bf16*  wt_proj = (bf16*)alloc((size_t)R_PW * 2);
    bf16*  wt_klin = (bf16*)alloc((size_t)R_KW * 2);
    float* a_e0s = (float*)alloc((size_t)N_AUTHOR * HEADS * 4);
    float* a_e0d = (float*)alloc((size_t)N_PAPER  * HEADS * 4);
    float* a_e1s = (float*)alloc((size_t)N_PAPER  * HEADS * 4);
    float* a_e1d = (float*)alloc((size_t)N_AUTHOR * HEADS * 4);
    float* a_e2s = (float*)alloc((size_t)N_PAPER  * HEADS * 4);
    float* a_e2d = (float*)alloc((size_t)N_PAPER  * HEADS * 4);
    float* score  = (float*)alloc(64);
    int* roff0 = (int*)alloc((size_t)(N_PAPER  + 1) * 4);
    int* roff1 = (int*)alloc((size_t)(N_AUTHOR + 1) * 4);
    int* roff2 = (int*)alloc((size_t)(N_PAPER  + 1) * 4);
    unsigned short* csrc0 = (unsigned short*)alloc((size_t)NEDGE * 2 + 64);
    unsigned short* csrc1 = (unsigned short*)alloc((size_t)NEDGE * 2 + 64);
    unsigned short* csrc2 = (unsigned short*)alloc((size_t)NEDGE * 2 + 64);
    int* cnt   = (int*)alloc((size_t)CNT_TOT * 4);
    unsigned short* rank = (unsigned short*)alloc((size_t)E3 * 2);
    int* bsum  = (int*)alloc(3 * 256 * 4);

    const int GA = (N_AUTHOR + 63) / 64;       // 313
    const int GP = (N_PAPER  + 63) / 64;       // 625
    const int NBMAX = (N_PAPER + 255) / 256;   // 157
    const int HB = (HIST_T + 255) / 256;       // 1172
    const int CONVB = (CONV_TOT + 255) / 256;
    const int NATTP = (N_PAPER * HEADS + 255) / 256;   // 1250
    const int NATTA = (N_AUTHOR * HEADS + 255) / 256;  // 625
    const int PGB = (N_PAPER + 15) / 16;       // 2500
    const int AGB = (N_AUTHOR + 15) / 16;      // 1250

    hipMemsetAsync(cnt, 0, (size_t)CNT_TOT * 4, stream);
    hipMemsetAsync(score, 0, 64, stream);

    // conversions first (small), then the atomic-bound hist with both
    // CSR-independent GEMMs hidden under its ~50us window.
    conv_kernel<<<CONVB, 256, 0, stream>>>(
        Wa, proj_w, klin_w, x_author, x_paper,
        wt_wa, wt_proj, wt_klin, xa, xp);
    hist_gemm_kernel<<<HB + GA + GP, 256, 0, stream>>>(
        ei_w + NEDGE, ei_wb + NEDGE, ei_c + NEDGE, cnt, rank, HB,
        xa, wt_wa, buf_a, GA,
        xp, wt_proj + (size_t)1 * HID * HID, proj_b + (size_t)1 * HID, xh_p);
    scan_a3_kernel<<<dim3(NBMAX, 3), 256, 0, stream>>>(cnt, bsum);
    scan_bc_kernel<<<dim3(NBMAX, 3), 256, 0, stream>>>(cnt, bsum, roff0, roff1, roff2);

    const float* as0_0 = att_src + 0 * HID; const float* ad0_0 = att_dst + 0 * HID;
    const float* as1_0 = att_src + 1 * HID; const float* ad1_0 = att_dst + 1 * HID;
    const float* as2_0 = att_src + 2 * HID; const float* ad2_0 = att_dst + 2 * HID;

    // fill + layer-0 author proj + layer-0 paper node-att hidden together
    fill_natt_kernel<<<HB + GA + NATTP, 256, 0, stream>>>(
        ei_w, ei_w + NEDGE, ei_wb, ei_wb + NEDGE, ei_c, ei_c + NEDGE,
        cnt, rank, csrc0, csrc1, csrc2, HB,
        buf_a, wt_proj + (size_t)0 * HID * HID, proj_b + (size_t)0 * HID, xh_a, GA,
        xh_p, ad0_0, as1_0, as2_0, ad2_0,
        a_e0d, a_e1s, a_e2s, a_e2d);
    node_att_multi_kernel<<<NATTA, 256, 0, stream>>>(
        xh_a, as0_0, ad1_0, a_e0s, a_e1d, N_AUTHOR);

    gather_fused_kernel<<<PGB + AGB, 256, 0, stream>>>(
        roff0, csrc0, a_e0s, a_e0d, xh_a,
        roff2, csrc2, a_e2s, a_e2d, xh_p,
        buf_p, agg_p1, PGB,
        roff1, csrc1, a_e1s, a_e1d, buf_a);

    // layer-0 klin scores
    bgemm_pair_kernel<128, 1, 0><<<2 * GP, 256, 0, stream>>>(
        buf_p, wt_klin, klin_b, (bf16*)nullptr, score + 0, N_PAPER, GP,
        agg_p1, nullptr, nullptr, wt_klin, klin_b, (bf16*)nullptr, score + 1, N_PAPER,
        qv);

    // layer-1 proj; paper side blends l0 semantic combine on the fly
    bgemm_pair_kernel<128, 0, 1><<<GA + GP, 256, 0, stream>>>(
        buf_a, wt_proj + (size_t)2 * HID * HID, proj_b + (size_t)2 * HID, xh_a,
        nullptr, N_AUTHOR, GA,
        buf_p, agg_p1, score,
        wt_proj + (size_t)3 * HID * HID, proj_b + (size_t)3 * HID, xh_p,
        nullptr, N_PAPER, nullptr);
    hipMemsetAsync(score, 0, 64, stream);

    const float* as0_1 = att_src + 3 * HID; const float* ad0_1 = att_dst + 3 * HID;
    const float* as2_1 = att_src + 5 * HID; const float* ad2_1 = att_dst + 5 * HID;

    natt_l1_kernel<<<NATTA + NATTP, 256, 0, stream>>>(
        xh_a, as0_1, a_e0s, NATTA,
        xh_p, ad0_1, as2_1, ad2_1, a_e0d, a_e2s, a_e2d);

    gather_fused_kernel<<<PGB, 256, 0, stream>>>(
        roff0, csrc0, a_e0s, a_e0d, xh_a,
        roff2, csrc2, a_e2s, a_e2d, xh_p,
        buf_p, agg_p1, PGB,
        roff1, csrc1, a_e1s, a_e1d, nullptr);

    bgemm_pair_kernel<128, 1, 0><<<2 * GP, 256, 0, stream>>>(
        buf_p, wt_klin + (size_t)HID * HID, klin_b + HID, (bf16*)nullptr, score + 0, N_PAPER, GP,
        agg_p1, nullptr, nullptr, wt_klin + (size_t)HID * HID, klin_b + HID,
        (bf16*)nullptr, score + 1, N_PAPER,
        qv + HID);

    final_lin_fused_kernel<<<(N_PAPER * NCLS + 255) / 256, 256, 0, stream>>>(
        buf_p, agg_p1, score, lin_w, lin_b, out);
}

// Round 3
// 412.524 us; speedup vs baseline: 1.0825x; 1.0364x over previous
//
#include <hip/hip_runtime.h>
#include <hip/hip_bf16.h>

typedef __hip_bfloat16 bf16;
typedef __hip_bfloat162 bf162;

#define N_AUTHOR 20000
#define N_PAPER  40000
#define NEDGE    400000
#define HID      128
#define HEADS    8
#define DIMH     16
#define NCLS     16

typedef short short8v __attribute__((ext_vector_type(8)));
typedef float f32x4   __attribute__((ext_vector_type(4)));

__device__ __forceinline__ float b2f(short s){
    return __uint_as_float(((unsigned)(unsigned short)s) << 16);
}
__device__ __forceinline__ short f2bs(float v){
    unsigned u = __float_as_uint(v);
    unsigned r = (u + 0x7FFFu + ((u >> 16) & 1u)) >> 16;
    return (short)r;
}
__device__ __forceinline__ float fastrcp(float x){ return __builtin_amdgcn_rcpf(x); }

__device__ __forceinline__ float fast_tanh(float x){
    x = fminf(fmaxf(x, -15.f), 15.f);
    float e = __expf(2.f * x);
    return 1.f - 2.f * fastrcp(e + 1.f);
}

// ---------------------------------------------------------------------------
// LDS-free bf16 MFMA GEMM body. A bf16 [M][KDIM] (or fp32 when AF32, converted
// in-register w/ RNE — bit-identical to pre-converted path); Wt bf16
// TRANSPOSED [128][KDIM]. BLEND: A-fragment = bf16(w0*A + w1*A2) on the fly.
// ---------------------------------------------------------------------------
template<int KDIM, int EPI, int BLEND, int AF32>
__device__ __forceinline__ void bgemm_body(
    const void* __restrict__ Av, const bf16* __restrict__ A2, float w0, float w1,
    const bf16* __restrict__ Wt, const float* __restrict__ Bb,
    bf16* __restrict__ C, const float* __restrict__ qv, float* __restrict__ score,
    int M, int brow, float* red)
{
    const int tid  = threadIdx.x;
    const int lane = tid & 63;
    const int wv   = tid >> 6;
    const int lr   = lane & 15;
    const int quad = lane >> 4;
    const int row0 = brow * 64 + wv * 16;
    const int arow_i = row0 + lr;
    const bool rowok = arow_i < M;

    short8v afrag[KDIM / 32];
    if (AF32) {
        const float* arow = (const float*)Av + (long)arow_i * KDIM;
        #pragma unroll
        for (int kc = 0; kc < KDIM / 32; kc++) {
            short8v f = {0,0,0,0,0,0,0,0};
            if (rowok) {
                float4 v0 = *(const float4*)(arow + kc * 32 + quad * 8);
                float4 v1 = *(const float4*)(arow + kc * 32 + quad * 8 + 4);
                f[0] = f2bs(v0.x); f[1] = f2bs(v0.y); f[2] = f2bs(v0.z); f[3] = f2bs(v0.w);
                f[4] = f2bs(v1.x); f[5] = f2bs(v1.y); f[6] = f2bs(v1.z); f[7] = f2bs(v1.w);
            }
            afrag[kc] = f;
        }
    } else {
        const bf16* arow  = (const bf16*)Av + (long)arow_i * KDIM;
        const bf16* arow2 = BLEND ? (A2 + (long)arow_i * KDIM) : nullptr;
        #pragma unroll
        for (int kc = 0; kc < KDIM / 32; kc++) {
            short8v f = {0,0,0,0,0,0,0,0};
            if (rowok) {
                f = *(const short8v*)(arow + kc * 32 + quad * 8);
                if (BLEND) {
                    short8v g = *(const short8v*)(arow2 + kc * 32 + quad * 8);
                    #pragma unroll
                    for (int j = 0; j < 8; j++)
                        f[j] = f2bs(w0 * b2f(f[j]) + w1 * b2f(g[j]));
                }
            }
            afrag[kc] = f;
        }
    }

    f32x4 acc[8];
    #pragma unroll
    for (int ct = 0; ct < 8; ct++) acc[ct] = (f32x4){0.f, 0.f, 0.f, 0.f};

    #pragma unroll
    for (int k0 = 0; k0 < KDIM / 32; k0 += 2) {
        short8v bf[2][8];
        #pragma unroll
        for (int u = 0; u < 2; u++)
            #pragma unroll
            for (int ct = 0; ct < 8; ct++)
                bf[u][ct] = *(const short8v*)(Wt + (long)(ct * 16 + lr) * KDIM + (k0 + u) * 32 + quad * 8);
        #pragma unroll
        for (int u = 0; u < 2; u++)
            #pragma unroll
            for (int ct = 0; ct < 8; ct++)
                acc[ct] = __builtin_amdgcn_mfma_f32_16x16x32_bf16(afrag[k0 + u], bf[u][ct], acc[ct], 0, 0, 0);
    }

    if (EPI == 0) {
        #pragma unroll
        for (int ct = 0; ct < 8; ct++) {
            float bc = Bb ? Bb[ct * 16 + lr] : 0.f;
            #pragma unroll
            for (int r = 0; r < 4; r++) {
                int orow = row0 + quad * 4 + r;
                if (orow < M)
                    C[(long)orow * HID + ct * 16 + lr] = __float2bfloat16(acc[ct][r] + bc);
            }
        }
    } else {
        float part = 0.f;
        #pragma unroll
        for (int ct = 0; ct < 8; ct++) {
            float bc = Bb ? Bb[ct * 16 + lr] : 0.f;
            float qc = qv[ct * 16 + lr];
            #pragma unroll
            for (int r = 0; r < 4; r++) {
                int orow = row0 + quad * 4 + r;
                if (orow < M) part += qc * fast_tanh(acc[ct][r] + bc);
            }
        }
        red[tid] = part;
        __syncthreads();
        for (int s = 128; s > 0; s >>= 1) {
            if (tid < s) red[tid] += red[tid + s];
            __syncthreads();
        }
        if (tid == 0) atomicAdd(score, red[0]);
    }
}

// pair kernel: side0 plain; side1 optionally blended (B1)
template<int KDIM, int EPI, int B1>
__global__ __launch_bounds__(256) void bgemm_pair_kernel(
    const bf16* __restrict__ A0, const bf16* __restrict__ Wt0, const float* __restrict__ Bb0,
    bf16* __restrict__ C0, float* __restrict__ score0, int M0, int NB0,
    const bf16* __restrict__ A1, const bf16* __restrict__ A1b, const float* __restrict__ scw,
    const bf16* __restrict__ Wt1, const float* __restrict__ Bb1,
    bf16* __restrict__ C1, float* __restrict__ score1, int M1,
    const float* __restrict__ qv)
{
    __shared__ float red[256];
    const int bx = blockIdx.x;
    if (bx < NB0) {
        bgemm_body<KDIM, EPI, 0, 0>(A0, nullptr, 0.f, 0.f, Wt0, Bb0, C0, qv, score0, M0, bx, red);
    } else {
        float w0 = 0.f, w1 = 0.f;
        if (B1) {
            float s0 = scw[0] * (1.f / N_PAPER);
            float s1 = scw[1] * (1.f / N_PAPER);
            float m = fmaxf(s0, s1);
            float e0 = __expf(s0 - m), e1 = __expf(s1 - m);
            float inv = fastrcp(e0 + e1);
            w0 = e0 * inv; w1 = e1 * inv;
        }
        bgemm_body<KDIM, EPI, B1, 0>(A1, A1b, w0, w1, Wt1, Bb1, C1, qv, score1, M1, bx - NB0, red);
    }
}

// ---------------------------------------------------------------------------
// sizes for conversions / CSR
// ---------------------------------------------------------------------------
#define R_WA  (128 * 64)
#define R_PW  (4 * 128 * 128)
#define R_KW  (2 * 128 * 128)
#define CONV_W_TOT (R_WA + R_PW + R_KW)

#define CNT_OFF1 N_PAPER
#define CNT_OFF2 (N_PAPER + N_AUTHOR)
#define NDEST    (2 * N_PAPER + N_AUTHOR)
#define NCOPY 8
#define CW    2
#define CIDX(c, d) (((c) * NDEST + (d)) * CW)
#define CNT_TOT (NCOPY * NDEST * CW)
#define E3 (3 * NEDGE)
#define HU 16
#define HIST_TT (E3 / HU)     // 75000 threads, 16 edges each

// weight conversions only (fp32->bf16, transposed)
__global__ __launch_bounds__(256) void convw_kernel(
    const float* __restrict__ Wa, const float* __restrict__ proj_w,
    const float* __restrict__ klin_w,
    bf16* __restrict__ wt_wa, bf16* __restrict__ wt_proj, bf16* __restrict__ wt_klin)
{
    int i = blockIdx.x * 256 + threadIdx.x;
    if (i >= CONV_W_TOT) return;
    if (i < R_WA) {
        int n = i >> 6, k = i & 63;
        wt_wa[i] = __float2bfloat16(Wa[k * 128 + n]);
    } else if (i < R_WA + R_PW) {
        int j = i - R_WA;
        int m = j >> 14, r = j & 16383;
        int n = r >> 7, k = r & 127;
        wt_proj[j] = __float2bfloat16(proj_w[m * 16384 + k * 128 + n]);
    } else {
        int j = i - R_WA - R_PW;
        int m = j >> 14, r = j & 16383;
        int n = r >> 7, k = r & 127;
        wt_klin[j] = __float2bfloat16(klin_w[m * 16384 + k * 128 + n]);
    }
}

// ---------------------------------------------------------------------------
// Fused: hist (atomic-queue-bound, ~50us floor; 16 edges/thread so it only
// occupies ~9 waves/CU, leaving slots for GEMM co-residency) + bufa K=64 GEMM
// + layer-0 paper projection GEMM, both reading raw fp32 A.
// ---------------------------------------------------------------------------
__global__ __launch_bounds__(256) void hist_gemm_kernel(
    const int* __restrict__ d0, const int* __restrict__ d1, const int* __restrict__ d2,
    int* __restrict__ cnt, unsigned short* __restrict__ rank, int HB,
    const float* __restrict__ xa_f, const bf16* __restrict__ wt_wa, bf16* __restrict__ buf_a, int GA64,
    const float* __restrict__ xp_f, const bf16* __restrict__ pw_p, const float* __restrict__ pb_p,
    bf16* __restrict__ xh_p)
{
    __shared__ float red[256];
    int bx = blockIdx.x;
    if (bx < HB) {
        int c = bx & (NCOPY - 1);
        int* mycnt = cnt + c * NDEST * CW;
        int t = bx * 256 + threadIdx.x;
        if (t >= HIST_TT) return;
        #pragma unroll
        for (int u = 0; u < HU; u++) {
            int i = t + u * HIST_TT;
            int r;
            if (i < NEDGE)            r = atomicAdd(&mycnt[d0[i] * CW], 1);
            else if (i < 2*NEDGE)     r = atomicAdd(&mycnt[(CNT_OFF1 + d1[i - NEDGE]) * CW], 1);
            else                      r = atomicAdd(&mycnt[(CNT_OFF2 + d2[i - 2*NEDGE]) * CW], 1);
            rank[i] = (unsigned short)((c << 13) | r);
        }
        return;
    }
    bx -= HB;
    if (bx < GA64) {
        bgemm_body<64, 0, 0, 1>(xa_f, nullptr, 0.f, 0.f, wt_wa, nullptr, buf_a,
                                nullptr, nullptr, N_AUTHOR, bx, red);
        return;
    }
    bx -= GA64;
    bgemm_body<128, 0, 0, 1>(xp_f, nullptr, 0.f, 0.f, pw_p, pb_p, xh_p,
                             nullptr, nullptr, N_PAPER, bx, red);
}

__device__ __forceinline__ int job_nd(int j){ return j == 1 ? N_AUTHOR : N_PAPER; }
__device__ __forceinline__ int job_off(int j){ return j == 0 ? 0 : (j == 1 ? CNT_OFF1 : CNT_OFF2); }

__global__ __launch_bounds__(256) void scan_a3_kernel(const int* __restrict__ cnt,
                                                      int* __restrict__ bsum)
{
    int j = blockIdx.y;
    int nd = job_nd(j), off = job_off(j);
    __shared__ int s[256];
    int tid = threadIdx.x;
    int i = blockIdx.x * 256 + tid;
    int v = 0;
    if (i < nd) {
        #pragma unroll
        for (int c = 0; c < NCOPY; c++) v += cnt[CIDX(c, off + i)];
    }
    s[tid] = v;
    __syncthreads();
    for (int st = 128; st > 0; st >>= 1) {
        if (tid < st) s[tid] += s[tid + st];
        __syncthreads();
    }
    if (tid == 0) bsum[j * 256 + blockIdx.x] = s[0];
}

// merged scan_b+scan_c: block base computed locally from bsum; per-dest
// exclusive prefix -> roff; per-copy counts -> global base positions in cnt.
__global__ __launch_bounds__(256) void scan_bc_kernel(int* __restrict__ cnt,
    const int* __restrict__ bsum,
    int* __restrict__ roff0, int* __restrict__ roff1, int* __restrict__ roff2)
{
    int j = blockIdx.y;
    int nd = job_nd(j), off = job_off(j);
    int* roff = j == 0 ? roff0 : (j == 1 ? roff1 : roff2);
    __shared__ int sb[256];
    __shared__ int s[256];
    int tid = threadIdx.x;
    int bx = blockIdx.x;
    int nb = (nd + 255) / 256;
    int bvt = (tid < nb) ? bsum[j * 256 + tid] : 0;
    sb[tid] = bvt;
    __syncthreads();
    for (int o = 1; o < 256; o <<= 1) {
        int t = (tid >= o) ? sb[tid - o] : 0;
        __syncthreads();
        sb[tid] += t;
        __syncthreads();
    }
    int base0 = sb[bx] - bsum[j * 256 + bx];   // exclusive block base
    int i = bx * 256 + tid;
    int cc[NCOPY];
    int v = 0;
    if (i < nd) {
        #pragma unroll
        for (int c = 0; c < NCOPY; c++) { cc[c] = cnt[CIDX(c, off + i)]; v += cc[c]; }
    }
    s[tid] = v;
    __syncthreads();
    for (int o = 1; o < 256; o <<= 1) {
        int t = (tid >= o) ? s[tid - o] : 0;
        __syncthreads();
        s[tid] += t;
        __syncthreads();
    }
    if (i < nd) {
        int base = base0 + s[tid] - v;
        roff[i] = base;
        #pragma unroll
        for (int c = 0; c < NCOPY; c++) { cnt[CIDX(c, off + i)] = base; base += cc[c]; }
    }
    if (bx == 0 && tid == 0) roff[nd] = NEDGE;   // each edge type has exactly NEDGE edges
}

// ---------------------------------------------------------------------------
// Fused: CSR fill (16 edges/thread) + layer-0 author projection + layer-0
// paper node-att dots.
// ---------------------------------------------------------------------------
__global__ __launch_bounds__(256) void fill_natt_kernel(
    const int* __restrict__ s0, const int* __restrict__ d0,
    const int* __restrict__ s1, const int* __restrict__ d1,
    const int* __restrict__ s2, const int* __restrict__ d2,
    const int* __restrict__ cnt, const unsigned short* __restrict__ rank,
    unsigned short* __restrict__ c0, unsigned short* __restrict__ c1, unsigned short* __restrict__ c2,
    int HB,
    const bf16* __restrict__ A, const bf16* __restrict__ Wt, const float* __restrict__ Bb,
    bf16* __restrict__ C, int GAb,
    const bf16* __restrict__ xh_p,
    const float* __restrict__ ad0v, const float* __restrict__ as1v,
    const float* __restrict__ as2v, const float* __restrict__ ad2v,
    float* __restrict__ o_e0d, float* __restrict__ o_e1s,
    float* __restrict__ o_e2s, float* __restrict__ o_e2d)
{
    __shared__ float red[256];
    int bx = blockIdx.x;
    if (bx < HB) {
        int t = bx * 256 + threadIdx.x;
        if (t >= HIST_TT) return;
        #pragma unroll
        for (int u = 0; u < HU; u++) {
            int i = t + u * HIST_TT;
            int rw = rank[i];
            int c = rw >> 13, rk = rw & 0x1FFF;
            if (i < NEDGE) {
                int d = d0[i];
                c0[cnt[CIDX(c, d)] + rk] = (unsigned short)s0[i];
            } else if (i < 2*NEDGE) {
                int e = i - NEDGE, d = d1[e];
                c1[cnt[CIDX(c, CNT_OFF1 + d)] + rk] = (unsigned short)s1[e];
            } else {
                int e = i - 2*NEDGE, d = d2[e];
                c2[cnt[CIDX(c, CNT_OFF2 + d)] + rk] = (unsigned short)s2[e];
            }
        }
        return;
    }
    bx -= HB;
    if (bx < GAb) {
        bgemm_body<128, 0, 0, 0>(A, nullptr, 0.f, 0.f, Wt, Bb, C,
                                 nullptr, nullptr, N_AUTHOR, bx, red);
        return;
    }
    bx -= GAb;
    int i = bx * 256 + threadIdx.x;
    if (i >= N_PAPER * HEADS) return;
    int n = i >> 3, h = i & 7;
    const bf16* row = xh_p + (long)n * HID + h * DIMH;
    float x[DIMH];
    #pragma unroll
    for (int d = 0; d < DIMH; d++) x[d] = __bfloat162float(row[d]);
    float sA = 0.f, sB = 0.f, sC = 0.f, sD = 0.f;
    #pragma unroll
    for (int d = 0; d < DIMH; d++) {
        sA += x[d] * ad0v[h*DIMH + d];
        sB += x[d] * as1v[h*DIMH + d];
        sC += x[d] * as2v[h*DIMH + d];
        sD += x[d] * ad2v[h*DIMH + d];
    }
    o_e0d[i] = sA; o_e1s[i] = sB; o_e2s[i] = sC; o_e2d[i] = sD;
}

// multi-output node attention dots (layer-0 author side)
__global__ void node_att_multi_kernel(const bf16* __restrict__ xh,
    const float* __restrict__ A0, const float* __restrict__ A1,
    float* __restrict__ O0, float* __restrict__ O1, int N)
{
    int i = blockIdx.x * blockDim.x + threadIdx.x;
    if (i >= N * HEADS) return;
    int n = i >> 3, h = i & 7;
    const bf16* row = xh + (long)n * HID + h * DIMH;
    float x[DIMH];
    #pragma unroll
    for (int d = 0; d < DIMH; d++) x[d] = __bfloat162float(row[d]);
    if (A0) { float s = 0.f;
        #pragma unroll
        for (int d = 0; d < DIMH; d++) s += x[d] * A0[h*DIMH + d];
        O0[i] = s; }
    if (A1) { float s = 0.f;
        #pragma unroll
        for (int d = 0; d < DIMH; d++) s += x[d] * A1[h*DIMH + d];
        O1[i] = s; }
}

// layer-1 fused node-att (author as0 only; paper ad0/as2/ad2)
__global__ __launch_bounds__(256) void natt_l1_kernel(
    const bf16* __restrict__ xh_a, const float* __restrict__ as0, float* __restrict__ a_e0s, int AB,
    const bf16* __restrict__ xh_p, const float* __restrict__ ad0,
    const float* __restrict__ as2, const float* __restrict__ ad2,
    float* __restrict__ a_e0d, float* __restrict__ a_e2s, float* __restrict__ a_e2d)
{
    int bx = blockIdx.x, tid = threadIdx.x;
    if (bx < AB) {
        int i = bx * 256 + tid;
        if (i >= N_AUTHOR * HEADS) return;
        int n = i >> 3, h = i & 7;
        const bf16* row = xh_a + (long)n * HID + h * DIMH;
        float s = 0.f;
        #pragma unroll
        for (int d = 0; d < DIMH; d++) s += __bfloat162float(row[d]) * as0[h*DIMH + d];
        a_e0s[i] = s;
        return;
    }
    int i = (bx - AB) * 256 + tid;
    if (i >= N_PAPER * HEADS) return;
    int n = i >> 3, h = i & 7;
    const bf16* row = xh_p + (long)n * HID + h * DIMH;
    float x[DIMH];
    #pragma unroll
    for (int d = 0; d < DIMH; d++) x[d] = __bfloat162float(row[d]);
    float sA = 0.f, sC = 0.f, sD = 0.f;
    #pragma unroll
    for (int d = 0; d < DIMH; d++) {
        sA += x[d] * ad0[h*DIMH + d];
        sC += x[d] * as2[h*DIMH + d];
        sD += x[d] * ad2[h*DIMH + d];
    }
    a_e0d[i] = sA; a_e2s[i] = sC; a_e2d[i] = sD;
}

// ---------------------------------------------------------------------------
// gather bodies (16 lanes per dest, lane owns 8 features, 4-deep batch)
// ---------------------------------------------------------------------------
__device__ __forceinline__ void paper_gather2_dev(int bid,
    const int* __restrict__ roff0, const unsigned short* __restrict__ csrc0,
    const float* __restrict__ as0, const float* __restrict__ ad0,
    const bf16* __restrict__ xha,
    const int* __restrict__ roff2, const unsigned short* __restrict__ csrc2,
    const float* __restrict__ as2, const float* __restrict__ ad2,
    const bf16* __restrict__ xhp,
    bf16* __restrict__ out0, bf16* __restrict__ out2)
{
    int lane = threadIdx.x & 63;
    int li   = lane & 15;
    int sub  = lane >> 4;
    int w = bid * 16 + (threadIdx.x >> 6) * 4 + sub;
    if (w >= N_PAPER) return;
    int h = li >> 1;

    int b0 = roff0[w], n0 = roff0[w + 1] - b0;
    int b2 = roff2[w], n2 = roff2[w + 1] - b2;
    float ad0v = ad0[(long)w * 8 + h];
    float ad2v = ad2[(long)w * 8 + h];
    float den0 = 0.f, den2 = 0.f;
    float acc0[8], acc2[8];
    #pragma unroll
    for (int j = 0; j < 8; j++) { acc0[j] = 0.f; acc2[j] = 0.f; }

    int nmax = n0 > n2 ? n0 : n2;
    int c0m = n0 > 0 ? n0 - 1 : 0;
    int c2m = n2 > 0 ? n2 - 1 : 0;
    for (int i = 0; i < nmax; i += 4) {
        int sA[4], sB[4];
        #pragma unroll
        for (int u = 0; u < 4; u++) {
            sA[u] = csrc0[b0 + min(i + u, c0m)];
            sB[u] = csrc2[b2 + min(i + u, c2m)];
        }
        float aA[4], aB[4];
        short8v xA[4], xB[4];
        #pragma unroll
        for (int u = 0; u < 4; u++) {
            aA[u] = as0[(long)sA[u] * 8 + h];
            xA[u] = *(const short8v*)(xha + (long)sA[u] * HID + li * 8);
            aB[u] = as2[(long)sB[u] * 8 + h];
            xB[u] = *(const short8v*)(xhp + (long)sB[u] * HID + li * 8);
        }
        #pragma unroll
        for (int u = 0; u < 4; u++) {
            float a = aA[u] + ad0v;
            a = a >= 0.f ? a : 0.2f * a;
            float wt = __expf(fminf(a, 60.f));
            wt = (i + u < n0) ? wt : 0.f;
            den0 += wt;
            #pragma unroll
            for (int j = 0; j < 8; j++)
                acc0[j] = fmaf(b2f(xA[u][j]), wt, acc0[j]);
            a = aB[u] + ad2v;
            a = a >= 0.f ? a : 0.2f * a;
            wt = __expf(fminf(a, 60.f));
            wt = (i + u < n2) ? wt : 0.f;
            den2 += wt;
            #pragma unroll
            for (int j = 0; j < 8; j++)
                acc2[j] = fmaf(b2f(xB[u][j]), wt, acc2[j]);
        }
    }
    float inv0 = fastrcp(den0 + 1e-16f);
    float inv2 = fastrcp(den2 + 1e-16f);
    short8v o0, o2;
    #pragma unroll
    for (int j = 0; j < 8; j++) {
        o0[j] = f2bs(fmaxf(acc0[j] * inv0, 0.f));
        o2[j] = f2bs(fmaxf(acc2[j] * inv2, 0.f));
    }
    *(short8v*)(out0 + (long)w * HID + li * 8) = o0;
    *(short8v*)(out2 + (long)w * HID + li * 8) = o2;
}

__device__ __forceinline__ void edge_gather_dev(int bid,
    const int* __restrict__ roff, const unsigned short* __restrict__ csrc,
    const float* __restrict__ as_, const float* __restrict__ ad_,
    const bf16* __restrict__ xh, bf16* __restrict__ out, int Ndst)
{
    int lane = threadIdx.x & 63;
    int li   = lane & 15;
    int sub  = lane >> 4;
    int w = bid * 16 + (threadIdx.x >> 6) * 4 + sub;
    if (w >= Ndst) return;
    int h = li >> 1;
    int beg = roff[w], n = roff[w + 1] - beg;
    float adv = ad_[(long)w * 8 + h];
    float den = 0.f;
    float acc[8];
    #pragma unroll
    for (int j = 0; j < 8; j++) acc[j] = 0.f;
    int cm = n > 0 ? n - 1 : 0;
    for (int i = 0; i < n; i += 4) {
        int s[4];
        #pragma unroll
        for (int u = 0; u < 4; u++) s[u] = csrc[beg + min(i + u, cm)];
        float av[4]; short8v xv[4];
        #pragma unroll
        for (int u = 0; u < 4; u++) {
            av[u] = as_[(long)s[u] * 8 + h];
            xv[u] = *(const short8v*)(xh + (long)s[u] * HID + li * 8);
        }
        #pragma unroll
        for (int u = 0; u < 4; u++) {
            float a = av[u] + adv;
            a = a >= 0.f ? a : 0.2f * a;
            float wt = __expf(fminf(a, 60.f));
            wt = (i + u < n) ? wt : 0.f;
            den += wt;
            #pragma unroll
            for (int j = 0; j < 8; j++)
                acc[j] = fmaf(b2f(xv[u][j]), wt, acc[j]);
        }
    }
    float inv = fastrcp(den + 1e-16f);
    short8v o;
    #pragma unroll
    for (int j = 0; j < 8; j++) o[j] = f2bs(fmaxf(acc[j] * inv, 0.f));
    *(short8v*)(out + (long)w * HID + li * 8) = o;
}

__global__ __launch_bounds__(256) void gather_fused_kernel(
    const int* __restrict__ roff0, const unsigned short* __restrict__ csrc0,
    const float* __restrict__ as0, const float* __restrict__ ad0,
    const bf16* __restrict__ xha,
    const int* __restrict__ roff2, const unsigned short* __restrict__ csrc2,
    const float* __restrict__ as2, const float* __restrict__ ad2,
    const bf16* __restrict__ xhp,
    bf16* __restrict__ out0, bf16* __restrict__ out2, int PB,
    const int* __restrict__ roff1, const unsigned short* __restrict__ csrc1,
    const float* __restrict__ as1, const float* __restrict__ ad1,
    bf16* __restrict__ out_a)
{
    int bx = blockIdx.x;
    if (bx < PB)
        paper_gather2_dev(bx, roff0, csrc0, as0, ad0, xha,
                          roff2, csrc2, as2, ad2, xhp, out0, out2);
    else
        edge_gather_dev(bx - PB, roff1, csrc1, as1, ad1, xhp, out_a, N_AUTHOR);
}

// final linear fused with last-layer semantic combine
__global__ __launch_bounds__(256) void final_lin_fused_kernel(
    const bf16* __restrict__ a0, const bf16* __restrict__ a1,
    const float* __restrict__ score,
    const float* __restrict__ W, const float* __restrict__ B, float* __restrict__ out)
{
    __shared__ float Ws[HID * NCLS];
    int tid = threadIdx.x;
    for (int i = tid; i < HID * NCLS; i += 256) Ws[i] = W[i];
    __syncthreads();
    float s0 = score[0] * (1.f / N_PAPER);
    float s1 = score[1] * (1.f / N_PAPER);
    float m = fmaxf(s0, s1);
    float e0 = __expf(s0 - m), e1 = __expf(s1 - m);
    float inv = 1.f / (e0 + e1);
    float w0 = e0 * inv, w1 = e1 * inv;
    int i = blockIdx.x * 256 + tid;
    if (i >= N_PAPER * NCLS) return;
    int n = i >> 4, c = i & 15;
    float acc = B[c];
    const bf16* x0 = a0 + (long)n * HID;
    const bf16* x1 = a1 + (long)n * HID;
    #pragma unroll 16
    for (int k = 0; k < HID; k++)
        acc = fmaf(fmaf(w0, __bfloat162float(x0[k]), w1 * __bfloat162float(x1[k])),
                   Ws[k * NCLS + c], acc);
    out[i] = acc;
}

extern "C" void kernel_launch(void* const* d_in, const int* in_sizes, int n_in,
                              void* d_out, int out_size, void* d_ws, size_t ws_size,
                              hipStream_t stream)
{
    const float* x_author = (const float*)d_in[0];
    const float* x_paper  = (const float*)d_in[1];
    const float* Wa       = (const float*)d_in[2];
    const float* proj_w   = (const float*)d_in[3];
    const float* proj_b   = (const float*)d_in[4];
    const float* att_src  = (const float*)d_in[5];
    const float* att_dst  = (const float*)d_in[6];
    const float* klin_w   = (const float*)d_in[7];
    const float* klin_b   = (const float*)d_in[8];
    const float* qv       = (const float*)d_in[9];
    const float* lin_w    = (const float*)d_in[10];
    const float* lin_b    = (const float*)d_in[11];
    const int*  ei_w      = (const int*)d_in[12];
    const int*  ei_wb     = (const int*)d_in[13];
    const int*  ei_c      = (const int*)d_in[14];
    float* out = (float*)d_out;
    (void)ws_size; (void)in_sizes; (void)n_in; (void)out_size;

    char* base = (char*)d_ws;
    size_t off = 0;
    auto alloc = [&](size_t bytes) {
        void* p = base + off;
        off = (off + bytes + 255) & ~(size_t)255;
        return p;
    };
    bf16*  xh_a  = (bf16*) alloc((size_t)N_AUTHOR * HID * 2);
    bf16*  xh_p  = (bf16*) alloc((size_t)N_PAPER  * HID * 2);
    bf16*  buf_a = (bf16*) alloc((size_t)N_AUTHOR * HID * 2);
    bf16*  buf_p = (bf16*) alloc((size_t)N_PAPER  * HID * 2);
    bf16*  agg_p1= (bf16*) alloc((size_t)N_PAPER  * HID * 2);
    bf16*  wt_wa   = (bf16*)alloc((size_t)R_WA * 2);
    bf16*  wt_proj = (bf16*)alloc((size_t)R_PW * 2);
    bf16*  wt_klin = (bf16*)alloc((size_t)R_KW * 2);
    float* a_e0s = (float*)alloc((size_t)N_AUTHOR * HEADS * 4);
    float* a_e0d = (float*)alloc((size_t)N_PAPER  * HEADS * 4);
    float* a_e1s = (float*)alloc((size_t)N_PAPER  * HEADS * 4);
    float* a_e1d = (float*)alloc((size_t)N_AUTHOR * HEADS * 4);
    float* a_e2s = (float*)alloc((size_t)N_PAPER  * HEADS * 4);
    float* a_e2d = (float*)alloc((size_t)N_PAPER  * HEADS * 4);
    float* score  = (float*)alloc(64);
    int* roff0 = (int*)alloc((size_t)(N_PAPER  + 1) * 4);
    int* roff1 = (int*)alloc((size_t)(N_AUTHOR + 1) * 4);
    int* roff2 = (int*)alloc((size_t)(N_PAPER  + 1) * 4);
    unsigned short* csrc0 = (unsigned short*)alloc((size_t)NEDGE * 2 + 64);
    unsigned short* csrc1 = (unsigned short*)alloc((size_t)NEDGE * 2 + 64);
    unsigned short* csrc2 = (unsigned short*)alloc((size_t)NEDGE * 2 + 64);
    int* cnt   = (int*)alloc((size_t)CNT_TOT * 4);
    unsigned short* rank = (unsigned short*)alloc((size_t)E3 * 2);
    int* bsum  = (int*)alloc(3 * 256 * 4);

    const int GA = (N_AUTHOR + 63) / 64;       // 313
    const int GP = (N_PAPER  + 63) / 64;       // 625
    const int NBMAX = (N_PAPER + 255) / 256;   // 157
    const int HB = (HIST_TT + 255) / 256;      // 293
    const int CONVB = (CONV_W_TOT + 255) / 256;
    const int NATTP = (N_PAPER * HEADS + 255) / 256;   // 1250
    const int NATTA = (N_AUTHOR * HEADS + 255) / 256;  // 625
    const int PGB = (N_PAPER + 15) / 16;       // 2500
    const int AGB = (N_AUTHOR + 15) / 16;      // 1250

    hipMemsetAsync(cnt, 0, (size_t)CNT_TOT * 4, stream);
    hipMemsetAsync(score, 0, 64, stream);

    // weight conversion (tiny), then atomic-bound hist with both
    // CSR-independent GEMMs (fp32-A) co-resident under its ~50us window.
    convw_kernel<<<CONVB, 256, 0, stream>>>(
        Wa, proj_w, klin_w, wt_wa, wt_proj, wt_klin);
    hist_gemm_kernel<<<HB + GA + GP, 256, 0, stream>>>(
        ei_w + NEDGE, ei_wb + NEDGE, ei_c + NEDGE, cnt, rank, HB,
        x_author, wt_wa, buf_a, GA,
        x_paper, wt_proj + (size_t)1 * HID * HID, proj_b + (size_t)1 * HID, xh_p);
    scan_a3_kernel<<<dim3(NBMAX, 3), 256, 0, stream>>>(cnt, bsum);
    scan_bc_kernel<<<dim3(NBMAX, 3), 256, 0, stream>>>(cnt, bsum, roff0, roff1, roff2);

    const float* as0_0 = att_src + 0 * HID; const float* ad0_0 = att_dst + 0 * HID;
    const float* as1_0 = att_src + 1 * HID; const float* ad1_0 = att_dst + 1 * HID;
    const float* as2_0 = att_src + 2 * HID; const float* ad2_0 = att_dst + 2 * HID;

    // fill + layer-0 author proj + layer-0 paper node-att hidden together
    fill_natt_kernel<<<HB + GA + NATTP, 256, 0, stream>>>(
        ei_w, ei_w + NEDGE, ei_wb, ei_wb + NEDGE, ei_c, ei_c + NEDGE,
        cnt, rank, csrc0, csrc1, csrc2, HB,
        buf_a, wt_proj + (size_t)0 * HID * HID, proj_b + (size_t)0 * HID, xh_a, GA,
        xh_p, ad0_0, as1_0, as2_0, ad2_0,
        a_e0d, a_e1s, a_e2s, a_e2d);
    node_att_multi_kernel<<<NATTA, 256, 0, stream>>>(
        xh_a, as0_0, ad1_0, a_e0s, a_e1d, N_AUTHOR);

    gather_fused_kernel<<<PGB + AGB, 256, 0, stream>>>(
        roff0, csrc0, a_e0s, a_e0d, xh_a,
        roff2, csrc2, a_e2s, a_e2d, xh_p,
        buf_p, agg_p1, PGB,
        roff1, csrc1, a_e1s, a_e1d, buf_a);

    // layer-0 klin scores
    bgemm_pair_kernel<128, 1, 0><<<2 * GP, 256, 0, stream>>>(
        buf_p, wt_klin, klin_b, (bf16*)nullptr, score + 0, N_PAPER, GP,
        agg_p1, nullptr, nullptr, wt_klin, klin_b, (bf16*)nullptr, score + 1, N_PAPER,
        qv);

    // layer-1 proj; paper side blends l0 semantic combine on the fly
    bgemm_pair_kernel<128, 0, 1><<<GA + GP, 256, 0, stream>>>(
        buf_a, wt_proj + (size_t)2 * HID * HID, proj_b + (size_t)2 * HID, xh_a,
        nullptr, N_AUTHOR, GA,
        buf_p, agg_p1, score,
        wt_proj + (size_t)3 * HID * HID, proj_b + (size_t)3 * HID, xh_p,
        nullptr, N_PAPER, nullptr);
    hipMemsetAsync(score, 0, 64, stream);

    const float* as0_1 = att_src + 3 * HID; const float* ad0_1 = att_dst + 3 * HID;
    const float* as2_1 = att_src + 5 * HID; const float* ad2_1 = att_dst + 5 * HID;

    natt_l1_kernel<<<NATTA + NATTP, 256, 0, stream>>>(
        xh_a, as0_1, a_e0s, NATTA,
        xh_p, ad0_1, as2_1, ad2_1, a_e0d, a_e2s, a_e2d);

    gather_fused_kernel<<<PGB, 256, 0, stream>>>(
        roff0, csrc0, a_e0s, a_e0d, xh_a,
        roff2, csrc2, a_e2s, a_e2d, xh_p,
        buf_p, agg_p1, PGB,
        roff1, csrc1, a_e1s, a_e1d, nullptr);

    bgemm_pair_kernel<128, 1, 0><<<2 * GP, 256, 0, stream>>>(
        buf_p, wt_klin + (size_t)HID * HID, klin_b + HID, (bf16*)nullptr, score + 0, N_PAPER, GP,
        agg_p1, nullptr, nullptr, wt_klin + (size_t)HID * HID, klin_b + HID,
        (bf16*)nullptr, score + 1, N_PAPER,
        qv + HID);

    final_lin_fused_kernel<<<(N_PAPER * NCLS + 255) / 256, 256, 0, stream>>>(
        buf_p, agg_p1, score, lin_w, lin_b, out);
}

// Round 4
// 395.412 us; speedup vs baseline: 1.1294x; 1.0433x over previous
//
#include <hip/hip_runtime.h>
#include <hip/hip_bf16.h>

typedef __hip_bfloat16 bf16;
typedef __hip_bfloat162 bf162;

#define N_AUTHOR 20000
#define N_PAPER  40000
#define NEDGE    400000
#define HID      128
#define HEADS    8
#define DIMH     16
#define NCLS     16

typedef short short8v __attribute__((ext_vector_type(8)));
typedef float f32x4   __attribute__((ext_vector_type(4)));

__device__ __forceinline__ float b2f(short s){
    return __uint_as_float(((unsigned)(unsigned short)s) << 16);
}
__device__ __forceinline__ short f2bs(float v){
    unsigned u = __float_as_uint(v);
    unsigned r = (u + 0x7FFFu + ((u >> 16) & 1u)) >> 16;
    return (short)r;
}
__device__ __forceinline__ float fastrcp(float x){ return __builtin_amdgcn_rcpf(x); }

__device__ __forceinline__ float fast_tanh(float x){
    x = fminf(fmaxf(x, -15.f), 15.f);
    float e = __expf(2.f * x);
    return 1.f - 2.f * fastrcp(e + 1.f);
}

// ---------------------------------------------------------------------------
// LDS-free bf16 MFMA GEMM body. A bf16 [M][KDIM] (or fp32 when AF32, converted
// in-register w/ RNE — bit-identical to pre-converted path); Wt bf16
// TRANSPOSED [128][KDIM]. BLEND: A-fragment = bf16(w0*A + w1*A2) on the fly.
// ---------------------------------------------------------------------------
template<int KDIM, int EPI, int BLEND, int AF32>
__device__ __forceinline__ void bgemm_body(
    const void* __restrict__ Av, const bf16* __restrict__ A2, float w0, float w1,
    const bf16* __restrict__ Wt, const float* __restrict__ Bb,
    bf16* __restrict__ C, const float* __restrict__ qv, float* __restrict__ score,
    int M, int brow, float* red)
{
    const int tid  = threadIdx.x;
    const int lane = tid & 63;
    const int wv   = tid >> 6;
    const int lr   = lane & 15;
    const int quad = lane >> 4;
    const int row0 = brow * 64 + wv * 16;
    const int arow_i = row0 + lr;
    const bool rowok = arow_i < M;

    short8v afrag[KDIM / 32];
    if (AF32) {
        const float* arow = (const float*)Av + (long)arow_i * KDIM;
        #pragma unroll
        for (int kc = 0; kc < KDIM / 32; kc++) {
            short8v f = {0,0,0,0,0,0,0,0};
            if (rowok) {
                float4 v0 = *(const float4*)(arow + kc * 32 + quad * 8);
                float4 v1 = *(const float4*)(arow + kc * 32 + quad * 8 + 4);
                f[0] = f2bs(v0.x); f[1] = f2bs(v0.y); f[2] = f2bs(v0.z); f[3] = f2bs(v0.w);
                f[4] = f2bs(v1.x); f[5] = f2bs(v1.y); f[6] = f2bs(v1.z); f[7] = f2bs(v1.w);
            }
            afrag[kc] = f;
        }
    } else {
        const bf16* arow  = (const bf16*)Av + (long)arow_i * KDIM;
        const bf16* arow2 = BLEND ? (A2 + (long)arow_i * KDIM) : nullptr;
        #pragma unroll
        for (int kc = 0; kc < KDIM / 32; kc++) {
            short8v f = {0,0,0,0,0,0,0,0};
            if (rowok) {
                f = *(const short8v*)(arow + kc * 32 + quad * 8);
                if (BLEND) {
                    short8v g = *(const short8v*)(arow2 + kc * 32 + quad * 8);
                    #pragma unroll
                    for (int j = 0; j < 8; j++)
                        f[j] = f2bs(w0 * b2f(f[j]) + w1 * b2f(g[j]));
                }
            }
            afrag[kc] = f;
        }
    }

    f32x4 acc[8];
    #pragma unroll
    for (int ct = 0; ct < 8; ct++) acc[ct] = (f32x4){0.f, 0.f, 0.f, 0.f};

    #pragma unroll
    for (int k0 = 0; k0 < KDIM / 32; k0 += 2) {
        short8v bf[2][8];
        #pragma unroll
        for (int u = 0; u < 2; u++)
            #pragma unroll
            for (int ct = 0; ct < 8; ct++)
                bf[u][ct] = *(const short8v*)(Wt + (long)(ct * 16 + lr) * KDIM + (k0 + u) * 32 + quad * 8);
        #pragma unroll
        for (int u = 0; u < 2; u++)
            #pragma unroll
            for (int ct = 0; ct < 8; ct++)
                acc[ct] = __builtin_amdgcn_mfma_f32_16x16x32_bf16(afrag[k0 + u], bf[u][ct], acc[ct], 0, 0, 0);
    }

    if (EPI == 0) {
        #pragma unroll
        for (int ct = 0; ct < 8; ct++) {
            float bc = Bb ? Bb[ct * 16 + lr] : 0.f;
            #pragma unroll
            for (int r = 0; r < 4; r++) {
                int orow = row0 + quad * 4 + r;
                if (orow < M)
                    C[(long)orow * HID + ct * 16 + lr] = __float2bfloat16(acc[ct][r] + bc);
            }
        }
    } else {
        float part = 0.f;
        #pragma unroll
        for (int ct = 0; ct < 8; ct++) {
            float bc = Bb ? Bb[ct * 16 + lr] : 0.f;
            float qc = qv[ct * 16 + lr];
            #pragma unroll
            for (int r = 0; r < 4; r++) {
                int orow = row0 + quad * 4 + r;
                if (orow < M) part += qc * fast_tanh(acc[ct][r] + bc);
            }
        }
        red[tid] = part;
        __syncthreads();
        for (int s = 128; s > 0; s >>= 1) {
            if (tid < s) red[tid] += red[tid + s];
            __syncthreads();
        }
        if (tid == 0) atomicAdd(score, red[0]);
    }
}

// pair kernel: side0 plain; side1 optionally blended (B1)
template<int KDIM, int EPI, int B1>
__global__ __launch_bounds__(256) void bgemm_pair_kernel(
    const bf16* __restrict__ A0, const bf16* __restrict__ Wt0, const float* __restrict__ Bb0,
    bf16* __restrict__ C0, float* __restrict__ score0, int M0, int NB0,
    const bf16* __restrict__ A1, const bf16* __restrict__ A1b, const float* __restrict__ scw,
    const bf16* __restrict__ Wt1, const float* __restrict__ Bb1,
    bf16* __restrict__ C1, float* __restrict__ score1, int M1,
    const float* __restrict__ qv)
{
    __shared__ float red[256];
    const int bx = blockIdx.x;
    if (bx < NB0) {
        bgemm_body<KDIM, EPI, 0, 0>(A0, nullptr, 0.f, 0.f, Wt0, Bb0, C0, qv, score0, M0, bx, red);
    } else {
        float w0 = 0.f, w1 = 0.f;
        if (B1) {
            float s0 = scw[0] * (1.f / N_PAPER);
            float s1 = scw[1] * (1.f / N_PAPER);
            float m = fmaxf(s0, s1);
            float e0 = __expf(s0 - m), e1 = __expf(s1 - m);
            float inv = fastrcp(e0 + e1);
            w0 = e0 * inv; w1 = e1 * inv;
        }
        bgemm_body<KDIM, EPI, B1, 0>(A1, A1b, w0, w1, Wt1, Bb1, C1, qv, score1, M1, bx - NB0, red);
    }
}

// ---------------------------------------------------------------------------
// sizes for conversions / CSR
// ---------------------------------------------------------------------------
#define R_WA  (128 * 64)
#define R_PW  (4 * 128 * 128)
#define R_KW  (2 * 128 * 128)
#define CONV_W_TOT (R_WA + R_PW + R_KW)

#define CNT_OFF1 N_PAPER
#define CNT_OFF2 (N_PAPER + N_AUTHOR)
#define NDEST    (2 * N_PAPER + N_AUTHOR)
#define NCOPY 8
#define CW    2
#define CIDX(c, d) (((c) * NDEST + (d)) * CW)
#define CNT_TOT (NCOPY * NDEST * CW)
#define E3 (3 * NEDGE)
#define HU 16
#define HIST_TT (E3 / HU)     // 75000 threads, 16 edges each

// weight conversions only (fp32->bf16, transposed)
__global__ __launch_bounds__(256) void convw_kernel(
    const float* __restrict__ Wa, const float* __restrict__ proj_w,
    const float* __restrict__ klin_w,
    bf16* __restrict__ wt_wa, bf16* __restrict__ wt_proj, bf16* __restrict__ wt_klin)
{
    int i = blockIdx.x * 256 + threadIdx.x;
    if (i >= CONV_W_TOT) return;
    if (i < R_WA) {
        int n = i >> 6, k = i & 63;
        wt_wa[i] = __float2bfloat16(Wa[k * 128 + n]);
    } else if (i < R_WA + R_PW) {
        int j = i - R_WA;
        int m = j >> 14, r = j & 16383;
        int n = r >> 7, k = r & 127;
        wt_proj[j] = __float2bfloat16(proj_w[m * 16384 + k * 128 + n]);
    } else {
        int j = i - R_WA - R_PW;
        int m = j >> 14, r = j & 16383;
        int n = r >> 7, k = r & 127;
        wt_klin[j] = __float2bfloat16(klin_w[m * 16384 + k * 128 + n]);
    }
}

// ---------------------------------------------------------------------------
// Fused: hist (atomic-queue-bound, ~50us floor; 16 edges/thread so it only
// occupies ~9 waves/CU, leaving slots for GEMM co-residency) + bufa K=64 GEMM
// + layer-0 paper projection GEMM, both reading raw fp32 A.
// ---------------------------------------------------------------------------
__global__ __launch_bounds__(256) void hist_gemm_kernel(
    const int* __restrict__ d0, const int* __restrict__ d1, const int* __restrict__ d2,
    int* __restrict__ cnt, unsigned short* __restrict__ rank, int HB,
    const float* __restrict__ xa_f, const bf16* __restrict__ wt_wa, bf16* __restrict__ buf_a, int GA64,
    const float* __restrict__ xp_f, const bf16* __restrict__ pw_p, const float* __restrict__ pb_p,
    bf16* __restrict__ xh_p)
{
    __shared__ float red[256];
    int bx = blockIdx.x;
    if (bx < HB) {
        int c = bx & (NCOPY - 1);
        int* mycnt = cnt + c * NDEST * CW;
        int t = bx * 256 + threadIdx.x;
        if (t >= HIST_TT) return;
        #pragma unroll
        for (int u = 0; u < HU; u++) {
            int i = t + u * HIST_TT;
            int r;
            if (i < NEDGE)            r = atomicAdd(&mycnt[d0[i] * CW], 1);
            else if (i < 2*NEDGE)     r = atomicAdd(&mycnt[(CNT_OFF1 + d1[i - NEDGE]) * CW], 1);
            else                      r = atomicAdd(&mycnt[(CNT_OFF2 + d2[i - 2*NEDGE]) * CW], 1);
            rank[i] = (unsigned short)((c << 13) | r);
        }
        return;
    }
    bx -= HB;
    if (bx < GA64) {
        bgemm_body<64, 0, 0, 1>(xa_f, nullptr, 0.f, 0.f, wt_wa, nullptr, buf_a,
                                nullptr, nullptr, N_AUTHOR, bx, red);
        return;
    }
    bx -= GA64;
    bgemm_body<128, 0, 0, 1>(xp_f, nullptr, 0.f, 0.f, pw_p, pb_p, xh_p,
                             nullptr, nullptr, N_PAPER, bx, red);
}

__device__ __forceinline__ int job_nd(int j){ return j == 1 ? N_AUTHOR : N_PAPER; }
__device__ __forceinline__ int job_off(int j){ return j == 0 ? 0 : (j == 1 ? CNT_OFF1 : CNT_OFF2); }

__global__ __launch_bounds__(256) void scan_a3_kernel(const int* __restrict__ cnt,
                                                      int* __restrict__ bsum)
{
    int j = blockIdx.y;
    int nd = job_nd(j), off = job_off(j);
    __shared__ int s[256];
    int tid = threadIdx.x;
    int i = blockIdx.x * 256 + tid;
    int v = 0;
    if (i < nd) {
        #pragma unroll
        for (int c = 0; c < NCOPY; c++) v += cnt[CIDX(c, off + i)];
    }
    s[tid] = v;
    __syncthreads();
    for (int st = 128; st > 0; st >>= 1) {
        if (tid < st) s[tid] += s[tid + st];
        __syncthreads();
    }
    if (tid == 0) bsum[j * 256 + blockIdx.x] = s[0];
}

// merged scan_b+scan_c: block base computed locally from bsum; per-dest
// exclusive prefix -> roff; per-copy counts -> global base positions in cnt.
__global__ __launch_bounds__(256) void scan_bc_kernel(int* __restrict__ cnt,
    const int* __restrict__ bsum,
    int* __restrict__ roff0, int* __restrict__ roff1, int* __restrict__ roff2)
{
    int j = blockIdx.y;
    int nd = job_nd(j), off = job_off(j);
    int* roff = j == 0 ? roff0 : (j == 1 ? roff1 : roff2);
    __shared__ int sb[256];
    __shared__ int s[256];
    int tid = threadIdx.x;
    int bx = blockIdx.x;
    int nb = (nd + 255) / 256;
    int bvt = (tid < nb) ? bsum[j * 256 + tid] : 0;
    sb[tid] = bvt;
    __syncthreads();
    for (int o = 1; o < 256; o <<= 1) {
        int t = (tid >= o) ? sb[tid - o] : 0;
        __syncthreads();
        sb[tid] += t;
        __syncthreads();
    }
    int base0 = sb[bx] - bsum[j * 256 + bx];   // exclusive block base
    int i = bx * 256 + tid;
    int cc[NCOPY];
    int v = 0;
    if (i < nd) {
        #pragma unroll
        for (int c = 0; c < NCOPY; c++) { cc[c] = cnt[CIDX(c, off + i)]; v += cc[c]; }
    }
    s[tid] = v;
    __syncthreads();
    for (int o = 1; o < 256; o <<= 1) {
        int t = (tid >= o) ? s[tid - o] : 0;
        __syncthreads();
        s[tid] += t;
        __syncthreads();
    }
    if (i < nd) {
        int base = base0 + s[tid] - v;
        roff[i] = base;
        #pragma unroll
        for (int c = 0; c < NCOPY; c++) { cnt[CIDX(c, off + i)] = base; base += cc[c]; }
    }
    if (bx == 0 && tid == 0) roff[nd] = NEDGE;   // each edge type has exactly NEDGE edges
}

// ---------------------------------------------------------------------------
// Fused: CSR fill (16 edges/thread) + layer-0 author projection + layer-0
// paper node-att dots.
// ---------------------------------------------------------------------------
__global__ __launch_bounds__(256) void fill_natt_kernel(
    const int* __restrict__ s0, const int* __restrict__ d0,
    const int* __restrict__ s1, const int* __restrict__ d1,
    const int* __restrict__ s2, const int* __restrict__ d2,
    const int* __restrict__ cnt, const unsigned short* __restrict__ rank,
    unsigned short* __restrict__ c0, unsigned short* __restrict__ c1, unsigned short* __restrict__ c2,
    int HB,
    const bf16* __restrict__ A, const bf16* __restrict__ Wt, const float* __restrict__ Bb,
    bf16* __restrict__ C, int GAb,
    const bf16* __restrict__ xh_p,
    const float* __restrict__ ad0v, const float* __restrict__ as1v,
    const float* __restrict__ as2v, const float* __restrict__ ad2v,
    float* __restrict__ o_e0d, float* __restrict__ o_e1s,
    float* __restrict__ o_e2s, float* __restrict__ o_e2d)
{
    __shared__ float red[256];
    int bx = blockIdx.x;
    if (bx < HB) {
        int t = bx * 256 + threadIdx.x;
        if (t >= HIST_TT) return;
        #pragma unroll
        for (int u = 0; u < HU; u++) {
            int i = t + u * HIST_TT;
            int rw = rank[i];
            int c = rw >> 13, rk = rw & 0x1FFF;
            if (i < NEDGE) {
                int d = d0[i];
                c0[cnt[CIDX(c, d)] + rk] = (unsigned short)s0[i];
            } else if (i < 2*NEDGE) {
                int e = i - NEDGE, d = d1[e];
                c1[cnt[CIDX(c, CNT_OFF1 + d)] + rk] = (unsigned short)s1[e];
            } else {
                int e = i - 2*NEDGE, d = d2[e];
                c2[cnt[CIDX(c, CNT_OFF2 + d)] + rk] = (unsigned short)s2[e];
            }
        }
        return;
    }
    bx -= HB;
    if (bx < GAb) {
        bgemm_body<128, 0, 0, 0>(A, nullptr, 0.f, 0.f, Wt, Bb, C,
                                 nullptr, nullptr, N_AUTHOR, bx, red);
        return;
    }
    bx -= GAb;
    int i = bx * 256 + threadIdx.x;
    if (i >= N_PAPER * HEADS) return;
    int n = i >> 3, h = i & 7;
    const bf16* row = xh_p + (long)n * HID + h * DIMH;
    float x[DIMH];
    #pragma unroll
    for (int d = 0; d < DIMH; d++) x[d] = __bfloat162float(row[d]);
    float sA = 0.f, sB = 0.f, sC = 0.f, sD = 0.f;
    #pragma unroll
    for (int d = 0; d < DIMH; d++) {
        sA += x[d] * ad0v[h*DIMH + d];
        sB += x[d] * as1v[h*DIMH + d];
        sC += x[d] * as2v[h*DIMH + d];
        sD += x[d] * ad2v[h*DIMH + d];
    }
    o_e0d[i] = sA; o_e1s[i] = sB; o_e2s[i] = sC; o_e2d[i] = sD;
}

// multi-output node attention dots (layer-0 author side)
__global__ void node_att_multi_kernel(const bf16* __restrict__ xh,
    const float* __restrict__ A0, const float* __restrict__ A1,
    float* __restrict__ O0, float* __restrict__ O1, int N)
{
    int i = blockIdx.x * blockDim.x + threadIdx.x;
    if (i >= N * HEADS) return;
    int n = i >> 3, h = i & 7;
    const bf16* row = xh + (long)n * HID + h * DIMH;
    float x[DIMH];
    #pragma unroll
    for (int d = 0; d < DIMH; d++) x[d] = __bfloat162float(row[d]);
    if (A0) { float s = 0.f;
        #pragma unroll
        for (int d = 0; d < DIMH; d++) s += x[d] * A0[h*DIMH + d];
        O0[i] = s; }
    if (A1) { float s = 0.f;
        #pragma unroll
        for (int d = 0; d < DIMH; d++) s += x[d] * A1[h*DIMH + d];
        O1[i] = s; }
}

// layer-1 fused node-att (author as0 only; paper ad0/as2/ad2)
__global__ __launch_bounds__(256) void natt_l1_kernel(
    const bf16* __restrict__ xh_a, const float* __restrict__ as0, float* __restrict__ a_e0s, int AB,
    const bf16* __restrict__ xh_p, const float* __restrict__ ad0,
    const float* __restrict__ as2, const float* __restrict__ ad2,
    float* __restrict__ a_e0d, float* __restrict__ a_e2s, float* __restrict__ a_e2d)
{
    int bx = blockIdx.x, tid = threadIdx.x;
    if (bx < AB) {
        int i = bx * 256 + tid;
        if (i >= N_AUTHOR * HEADS) return;
        int n = i >> 3, h = i & 7;
        const bf16* row = xh_a + (long)n * HID + h * DIMH;
        float s = 0.f;
        #pragma unroll
        for (int d = 0; d < DIMH; d++) s += __bfloat162float(row[d]) * as0[h*DIMH + d];
        a_e0s[i] = s;
        return;
    }
    int i = (bx - AB) * 256 + tid;
    if (i >= N_PAPER * HEADS) return;
    int n = i >> 3, h = i & 7;
    const bf16* row = xh_p + (long)n * HID + h * DIMH;
    float x[DIMH];
    #pragma unroll
    for (int d = 0; d < DIMH; d++) x[d] = __bfloat162float(row[d]);
    float sA = 0.f, sC = 0.f, sD = 0.f;
    #pragma unroll
    for (int d = 0; d < DIMH; d++) {
        sA += x[d] * ad0[h*DIMH + d];
        sC += x[d] * as2[h*DIMH + d];
        sD += x[d] * ad2[h*DIMH + d];
    }
    a_e0d[i] = sA; a_e2s[i] = sC; a_e2d[i] = sD;
}

// ---------------------------------------------------------------------------
// Split gather: one wave handles 4 dests of ONE edge type; 8 rows in flight.
// Removes the max(n0,n2) clamped-redundant work of the fused version and
// doubles per-wave outstanding row loads.
// ---------------------------------------------------------------------------
template<int U>
__device__ __forceinline__ void gather1_dev(int bid,
    const int* __restrict__ roff, const unsigned short* __restrict__ csrc,
    const float* __restrict__ as_, const float* __restrict__ ad_,
    const bf16* __restrict__ xh, bf16* __restrict__ out, int Ndst)
{
    int lane = threadIdx.x & 63;
    int li   = lane & 15;
    int sub  = lane >> 4;
    int w = bid * 16 + (threadIdx.x >> 6) * 4 + sub;
    if (w >= Ndst) return;
    int h = li >> 1;
    int beg = roff[w], n = roff[w + 1] - beg;
    float adv = ad_[(long)w * 8 + h];
    float den = 0.f;
    float acc[8];
    #pragma unroll
    for (int j = 0; j < 8; j++) acc[j] = 0.f;
    int cm = n > 0 ? n - 1 : 0;
    for (int i = 0; i < n; i += U) {
        int s[U];
        #pragma unroll
        for (int u = 0; u < U; u++) s[u] = csrc[beg + min(i + u, cm)];
        float av[U]; short8v xv[U];
        #pragma unroll
        for (int u = 0; u < U; u++) {
            av[u] = as_[(long)s[u] * 8 + h];
            xv[u] = *(const short8v*)(xh + (long)s[u] * HID + li * 8);
        }
        #pragma unroll
        for (int u = 0; u < U; u++) {
            float a = av[u] + adv;
            a = a >= 0.f ? a : 0.2f * a;
            float wt = __expf(fminf(a, 60.f));
            wt = (i + u < n) ? wt : 0.f;
            den += wt;
            #pragma unroll
            for (int j = 0; j < 8; j++)
                acc[j] = fmaf(b2f(xv[u][j]), wt, acc[j]);
        }
    }
    float inv = fastrcp(den + 1e-16f);
    short8v o;
    #pragma unroll
    for (int j = 0; j < 8; j++) o[j] = f2bs(fmaxf(acc[j] * inv, 0.f));
    *(short8v*)(out + (long)w * HID + li * 8) = o;
}

__global__ __launch_bounds__(256) void gather_split_kernel(
    const int* __restrict__ roff0, const unsigned short* __restrict__ csrc0,
    const float* __restrict__ as0, const float* __restrict__ ad0,
    const bf16* __restrict__ xha, bf16* __restrict__ out0,
    const int* __restrict__ roff2, const unsigned short* __restrict__ csrc2,
    const float* __restrict__ as2, const float* __restrict__ ad2,
    const bf16* __restrict__ xhp, bf16* __restrict__ out2,
    int PB,
    const int* __restrict__ roff1, const unsigned short* __restrict__ csrc1,
    const float* __restrict__ as1, const float* __restrict__ ad1,
    bf16* __restrict__ out_a)
{
    int bx = blockIdx.x;
    if (bx < PB) {
        gather1_dev<8>(bx, roff0, csrc0, as0, ad0, xha, out0, N_PAPER);
        return;
    }
    bx -= PB;
    if (bx < PB) {
        gather1_dev<8>(bx, roff2, csrc2, as2, ad2, xhp, out2, N_PAPER);
        return;
    }
    bx -= PB;
    gather1_dev<8>(bx, roff1, csrc1, as1, ad1, xhp, out_a, N_AUTHOR);
}

// final linear fused with last-layer semantic combine
__global__ __launch_bounds__(256) void final_lin_fused_kernel(
    const bf16* __restrict__ a0, const bf16* __restrict__ a1,
    const float* __restrict__ score,
    const float* __restrict__ W, const float* __restrict__ B, float* __restrict__ out)
{
    __shared__ float Ws[HID * NCLS];
    int tid = threadIdx.x;
    for (int i = tid; i < HID * NCLS; i += 256) Ws[i] = W[i];
    __syncthreads();
    float s0 = score[0] * (1.f / N_PAPER);
    float s1 = score[1] * (1.f / N_PAPER);
    float m = fmaxf(s0, s1);
    float e0 = __expf(s0 - m), e1 = __expf(s1 - m);
    float inv = 1.f / (e0 + e1);
    float w0 = e0 * inv, w1 = e1 * inv;
    int i = blockIdx.x * 256 + tid;
    if (i >= N_PAPER * NCLS) return;
    int n = i >> 4, c = i & 15;
    float acc = B[c];
    const bf16* x0 = a0 + (long)n * HID;
    const bf16* x1 = a1 + (long)n * HID;
    #pragma unroll 16
    for (int k = 0; k < HID; k++)
        acc = fmaf(fmaf(w0, __bfloat162float(x0[k]), w1 * __bfloat162float(x1[k])),
                   Ws[k * NCLS + c], acc);
    out[i] = acc;
}

extern "C" void kernel_launch(void* const* d_in, const int* in_sizes, int n_in,
                              void* d_out, int out_size, void* d_ws, size_t ws_size,
                              hipStream_t stream)
{
    const float* x_author = (const float*)d_in[0];
    const float* x_paper  = (const float*)d_in[1];
    const float* Wa       = (const float*)d_in[2];
    const float* proj_w   = (const float*)d_in[3];
    const float* proj_b   = (const float*)d_in[4];
    const float* att_src  = (const float*)d_in[5];
    const float* att_dst  = (const float*)d_in[6];
    const float* klin_w   = (const float*)d_in[7];
    const float* klin_b   = (const float*)d_in[8];
    const float* qv       = (const float*)d_in[9];
    const float* lin_w    = (const float*)d_in[10];
    const float* lin_b    = (const float*)d_in[11];
    const int*  ei_w      = (const int*)d_in[12];
    const int*  ei_wb     = (const int*)d_in[13];
    const int*  ei_c      = (const int*)d_in[14];
    float* out = (float*)d_out;
    (void)ws_size; (void)in_sizes; (void)n_in; (void)out_size;

    char* base = (char*)d_ws;
    size_t off = 0;
    auto alloc = [&](size_t bytes) {
        void* p = base + off;
        off = (off + bytes + 255) & ~(size_t)255;
        return p;
    };
    bf16*  xh_a  = (bf16*) alloc((size_t)N_AUTHOR * HID * 2);
    bf16*  xh_p  = (bf16*) alloc((size_t)N_PAPER  * HID * 2);
    bf16*  buf_a = (bf16*) alloc((size_t)N_AUTHOR * HID * 2);
    bf16*  buf_p = (bf16*) alloc((size_t)N_PAPER  * HID * 2);
    bf16*  agg_p1= (bf16*) alloc((size_t)N_PAPER  * HID * 2);
    bf16*  wt_wa   = (bf16*)alloc((size_t)R_WA * 2);
    bf16*  wt_proj = (bf16*)alloc((size_t)R_PW * 2);
    bf16*  wt_klin = (bf16*)alloc((size_t)R_KW * 2);
    float* a_e0s = (float*)alloc((size_t)N_AUTHOR * HEADS * 4);
    float* a_e0d = (float*)alloc((size_t)N_PAPER  * HEADS * 4);
    float* a_e1s = (float*)alloc((size_t)N_PAPER  * HEADS * 4);
    float* a_e1d = (float*)alloc((size_t)N_AUTHOR * HEADS * 4);
    float* a_e2s = (float*)alloc((size_t)N_PAPER  * HEADS * 4);
    float* a_e2d = (float*)alloc((size_t)N_PAPER  * HEADS * 4);
    float* score  = (float*)alloc(64);
    int* roff0 = (int*)alloc((size_t)(N_PAPER  + 1) * 4);
    int* roff1 = (int*)alloc((size_t)(N_AUTHOR + 1) * 4);
    int* roff2 = (int*)alloc((size_t)(N_PAPER  + 1) * 4);
    unsigned short* csrc0 = (unsigned short*)alloc((size_t)NEDGE * 2 + 64);
    unsigned short* csrc1 = (unsigned short*)alloc((size_t)NEDGE * 2 + 64);
    unsigned short* csrc2 = (unsigned short*)alloc((size_t)NEDGE * 2 + 64);
    int* cnt   = (int*)alloc((size_t)CNT_TOT * 4);
    unsigned short* rank = (unsigned short*)alloc((size_t)E3 * 2);
    int* bsum  = (int*)alloc(3 * 256 * 4);

    const int GA = (N_AUTHOR + 63) / 64;       // 313
    const int GP = (N_PAPER  + 63) / 64;       // 625
    const int NBMAX = (N_PAPER + 255) / 256;   // 157
    const int HB = (HIST_TT + 255) / 256;      // 293
    const int CONVB = (CONV_W_TOT + 255) / 256;
    const int NATTP = (N_PAPER * HEADS + 255) / 256;   // 1250
    const int NATTA = (N_AUTHOR * HEADS + 255) / 256;  // 625
    const int PGB = (N_PAPER + 15) / 16;       // 2500
    const int AGB = (N_AUTHOR + 15) / 16;      // 1250

    hipMemsetAsync(cnt, 0, (size_t)CNT_TOT * 4, stream);
    hipMemsetAsync(score, 0, 64, stream);

    // weight conversion (tiny), then atomic-bound hist with both
    // CSR-independent GEMMs (fp32-A) co-resident under its ~50us window.
    convw_kernel<<<CONVB, 256, 0, stream>>>(
        Wa, proj_w, klin_w, wt_wa, wt_proj, wt_klin);
    hist_gemm_kernel<<<HB + GA + GP, 256, 0, stream>>>(
        ei_w + NEDGE, ei_wb + NEDGE, ei_c + NEDGE, cnt, rank, HB,
        x_author, wt_wa, buf_a, GA,
        x_paper, wt_proj + (size_t)1 * HID * HID, proj_b + (size_t)1 * HID, xh_p);
    scan_a3_kernel<<<dim3(NBMAX, 3), 256, 0, stream>>>(cnt, bsum);
    scan_bc_kernel<<<dim3(NBMAX, 3), 256, 0, stream>>>(cnt, bsum, roff0, roff1, roff2);

    const float* as0_0 = att_src + 0 * HID; const float* ad0_0 = att_dst + 0 * HID;
    const float* as1_0 = att_src + 1 * HID; const float* ad1_0 = att_dst + 1 * HID;
    const float* as2_0 = att_src + 2 * HID; const float* ad2_0 = att_dst + 2 * HID;

    // fill + layer-0 author proj + layer-0 paper node-att hidden together
    fill_natt_kernel<<<HB + GA + NATTP, 256, 0, stream>>>(
        ei_w, ei_w + NEDGE, ei_wb, ei_wb + NEDGE, ei_c, ei_c + NEDGE,
        cnt, rank, csrc0, csrc1, csrc2, HB,
        buf_a, wt_proj + (size_t)0 * HID * HID, proj_b + (size_t)0 * HID, xh_a, GA,
        xh_p, ad0_0, as1_0, as2_0, ad2_0,
        a_e0d, a_e1s, a_e2s, a_e2d);
    node_att_multi_kernel<<<NATTA, 256, 0, stream>>>(
        xh_a, as0_0, ad1_0, a_e0s, a_e1d, N_AUTHOR);

    gather_split_kernel<<<2 * PGB + AGB, 256, 0, stream>>>(
        roff0, csrc0, a_e0s, a_e0d, xh_a, buf_p,
        roff2, csrc2, a_e2s, a_e2d, xh_p, agg_p1,
        PGB,
        roff1, csrc1, a_e1s, a_e1d, buf_a);

    // layer-0 klin scores
    bgemm_pair_kernel<128, 1, 0><<<2 * GP, 256, 0, stream>>>(
        buf_p, wt_klin, klin_b, (bf16*)nullptr, score + 0, N_PAPER, GP,
        agg_p1, nullptr, nullptr, wt_klin, klin_b, (bf16*)nullptr, score + 1, N_PAPER,
        qv);

    // layer-1 proj; paper side blends l0 semantic combine on the fly
    bgemm_pair_kernel<128, 0, 1><<<GA + GP, 256, 0, stream>>>(
        buf_a, wt_proj + (size_t)2 * HID * HID, proj_b + (size_t)2 * HID, xh_a,
        nullptr, N_AUTHOR, GA,
        buf_p, agg_p1, score,
        wt_proj + (size_t)3 * HID * HID, proj_b + (size_t)3 * HID, xh_p,
        nullptr, N_PAPER, nullptr);
    hipMemsetAsync(score, 0, 64, stream);

    const float* as0_1 = att_src + 3 * HID; const float* ad0_1 = att_dst + 3 * HID;
    const float* as2_1 = att_src + 5 * HID; const float* ad2_1 = att_dst + 5 * HID;

    natt_l1_kernel<<<NATTA + NATTP, 256, 0, stream>>>(
        xh_a, as0_1, a_e0s, NATTA,
        xh_p, ad0_1, as2_1, ad2_1, a_e0d, a_e2s, a_e2d);

    gather_split_kernel<<<2 * PGB, 256, 0, stream>>>(
        roff0, csrc0, a_e0s, a_e0d, xh_a, buf_p,
        roff2, csrc2, a_e2s, a_e2d, xh_p, agg_p1,
        PGB,
        roff1, csrc1, a_e1s, a_e1d, nullptr);

    bgemm_pair_kernel<128, 1, 0><<<2 * GP, 256, 0, stream>>>(
        buf_p, wt_klin + (size_t)HID * HID, klin_b + HID, (bf16*)nullptr, score + 0, N_PAPER, GP,
        agg_p1, nullptr, nullptr, wt_klin + (size_t)HID * HID, klin_b + HID,
        (bf16*)nullptr, score + 1, N_PAPER,
        qv + HID);

    final_lin_fused_kernel<<<(N_PAPER * NCLS + 255) / 256, 256, 0, stream>>>(
        buf_p, agg_p1, score, lin_w, lin_b, out);
}